// Round 2
// baseline (8571.459 us; speedup 1.0000x reference)
//
#include <hip/hip_runtime.h>
#include <math.h>

// Sizes: B=32, N=128, EMB=1024, HID=512, L=2, NCLS=7, IN_DIM=3072, TOK=4096
// Scan: weight-stationary MFMA. 2 GNN pods x 64 WGs x 16 batches. Each WG
// owns 8 h-cols; waves 0-2 hold gate-weight tiles (6 gates x 8 cols) and
// wave 3 holds the V tile ({Wr0|Wr1} 8+8 cols) as bf16 hi/lo B-fragments in
// VGPRs (loaded once). Per step: stage M (bf16) -> 32 MFMAs -> gates/h local
// -> exchange h -> stage h -> V MFMA + hk + softmax + M'. Cross-WG sync is a
// store-flag barrier: each WG stores a monotonic seq to its own flag; wave 0
// polls all 64 flags with one coalesced agent load per iteration (no RMW
// convoy, no master relay). LSTM on WGs 128..255 (layer-0 launch).

typedef __attribute__((ext_vector_type(4))) float f32x4;
typedef __attribute__((ext_vector_type(8))) short s16x8;

#define AGENT __HIP_MEMORY_SCOPE_AGENT

__device__ __forceinline__ float ldc(const float* p) {
    return __hip_atomic_load(p, __ATOMIC_RELAXED, AGENT);
}
__device__ __forceinline__ void stc(float* p, float v) {
    __hip_atomic_store(p, v, __ATOMIC_RELAXED, AGENT);
}
__device__ __forceinline__ unsigned ldcu(const unsigned* p) {
    return __hip_atomic_load(p, __ATOMIC_RELAXED, AGENT);
}
__device__ __forceinline__ void stcu(unsigned* p, unsigned v) {
    __hip_atomic_store(p, v, __ATOMIC_RELAXED, AGENT);
}

// Store-flag pod barrier. All 64 WGs of a pod call with the same monotonic
// seq. Entry __syncthreads drains each thread's outstanding stores (vmcnt 0)
// so the flag store publishes them. Wave 0 polls all 64 flags (one coalesced
// 256B agent load per iteration).
__device__ __forceinline__ void podsig(unsigned* flags, int w, unsigned seq) {
    __syncthreads();
    if (threadIdx.x == 0) {
        __builtin_amdgcn_s_waitcnt(0);
        stcu(flags + w, seq);
    }
    if (threadIdx.x < 64) {
        while (ldcu(flags + threadIdx.x) < seq) {
            __builtin_amdgcn_s_sleep(1);
        }
    }
    __asm__ __volatile__("" ::: "memory");
    __syncthreads();
}

__global__ void init_bar(int* bar) { bar[threadIdx.x] = 0; }

__device__ __forceinline__ float sigf(float x) { return 1.f / (1.f + __expf(-x)); }

// fp32 -> bf16 (RNE) and back
__device__ __forceinline__ unsigned short f2bf(float f) {
    unsigned u = __float_as_uint(f);
    return (unsigned short)((u + 0x7fffu + ((u >> 16) & 1u)) >> 16);
}
__device__ __forceinline__ float bf2f(unsigned short h) {
    return __uint_as_float(((unsigned)h) << 16);
}

// ---------------------------------------------------------------------------
// Generic fp32 GEMM: C = act(A[M,K] @ W[N,K]^T + bias). 64x64 tile.
// ---------------------------------------------------------------------------
__global__ __launch_bounds__(256) void gemm_nt(
    const float* __restrict__ A, const float* __restrict__ W,
    const float* __restrict__ bias, float* __restrict__ C,
    int M, int N, int K, int relu)
{
    __shared__ float As[16][68];
    __shared__ float Ws[16][68];
    const int tid = threadIdx.x;
    const int m0 = blockIdx.x * 64;
    const int n0 = blockIdx.y * 64;
    const int lr = tid >> 2;
    const int lk = (tid & 3) << 2;
    const int tm = (tid & 15) << 2;
    const int tn = (tid >> 4) << 2;
    float acc[4][4] = {};
    const float* Aptr = A + (size_t)(m0 + lr) * K + lk;
    const float* Wptr = W + (size_t)(n0 + lr) * K + lk;
    for (int k0 = 0; k0 < K; k0 += 16) {
        __syncthreads();
        const float4 av = *(const float4*)(Aptr + k0);
        const float4 wv = *(const float4*)(Wptr + k0);
        As[lk + 0][lr] = av.x; As[lk + 1][lr] = av.y;
        As[lk + 2][lr] = av.z; As[lk + 3][lr] = av.w;
        Ws[lk + 0][lr] = wv.x; Ws[lk + 1][lr] = wv.y;
        Ws[lk + 2][lr] = wv.z; Ws[lk + 3][lr] = wv.w;
        __syncthreads();
        #pragma unroll
        for (int kk = 0; kk < 16; ++kk) {
            float a[4], b[4];
            #pragma unroll
            for (int u = 0; u < 4; ++u) { a[u] = As[kk][tm + u]; b[u] = Ws[kk][tn + u]; }
            #pragma unroll
            for (int ii = 0; ii < 4; ++ii)
                #pragma unroll
                for (int jj = 0; jj < 4; ++jj)
                    acc[ii][jj] += a[ii] * b[jj];
        }
    }
    #pragma unroll
    for (int ii = 0; ii < 4; ++ii)
        #pragma unroll
        for (int jj = 0; jj < 4; ++jj) {
            float v = acc[ii][jj] + bias[n0 + tn + jj];
            if (relu) v = fmaxf(v, 0.f);
            C[(size_t)(m0 + tm + ii) * N + n0 + tn + jj] = v;
        }
}

// ---------------------------------------------------------------------------
// mlp0 with fused 5-way concat
// ---------------------------------------------------------------------------
__global__ __launch_bounds__(256) void gemm_cat(
    const float* __restrict__ H0, const float* __restrict__ H1,
    const float* __restrict__ H2, const float* __restrict__ feat,
    const float* __restrict__ lstm, const float* __restrict__ W,
    const float* __restrict__ bias, float* __restrict__ C)
{
    __shared__ float As[16][68];
    __shared__ float Ws[16][68];
    const int tid = threadIdx.x;
    const int m0 = blockIdx.x * 64;
    const int n0 = blockIdx.y * 64;
    const int lr = tid >> 2;
    const int lk = (tid & 3) << 2;
    const int tm = (tid & 15) << 2;
    const int tn = (tid >> 4) << 2;
    float acc[4][4] = {};
    for (int k0 = 0; k0 < 3072; k0 += 16) {
        const float* src; int kloc, Kp;
        if (k0 < 512)       { src = H0;   kloc = k0;        Kp = 512;  }
        else if (k0 < 1024) { src = H1;   kloc = k0 - 512;  Kp = 512;  }
        else if (k0 < 1536) { src = H2;   kloc = k0 - 1024; Kp = 512;  }
        else if (k0 < 2560) { src = feat; kloc = k0 - 1536; Kp = 1024; }
        else                { src = lstm; kloc = k0 - 2560; Kp = 512;  }
        __syncthreads();
        const float4 av = *(const float4*)(src + (size_t)(m0 + lr) * Kp + kloc + lk);
        const float4 wv = *(const float4*)(W + (size_t)(n0 + lr) * 3072 + k0 + lk);
        As[lk + 0][lr] = av.x; As[lk + 1][lr] = av.y;
        As[lk + 2][lr] = av.z; As[lk + 3][lr] = av.w;
        Ws[lk + 0][lr] = wv.x; Ws[lk + 1][lr] = wv.y;
        Ws[lk + 2][lr] = wv.z; Ws[lk + 3][lr] = wv.w;
        __syncthreads();
        #pragma unroll
        for (int kk = 0; kk < 16; ++kk) {
            float a[4], b[4];
            #pragma unroll
            for (int u = 0; u < 4; ++u) { a[u] = As[kk][tm + u]; b[u] = Ws[kk][tn + u]; }
            #pragma unroll
            for (int ii = 0; ii < 4; ++ii)
                #pragma unroll
                for (int jj = 0; jj < 4; ++jj)
                    acc[ii][jj] += a[ii] * b[jj];
        }
    }
    #pragma unroll
    for (int ii = 0; ii < 4; ++ii)
        #pragma unroll
        for (int jj = 0; jj < 4; ++jj) {
            float v = fmaxf(acc[ii][jj] + bias[n0 + tn + jj], 0.f);
            C[(size_t)(m0 + tm + ii) * 512 + n0 + tn + jj] = v;
        }
}

// ---------------------------------------------------------------------------
// One GNN layer scan (weight-stationary MFMA). Grid 256 (layer 0) / 128.
// ---------------------------------------------------------------------------
__global__ __launch_bounds__(256, 1) void scan_layer(
    const float* __restrict__ Hin, float* __restrict__ Hout,
    const float* __restrict__ adj, const float* __restrict__ smk,
    const float* __restrict__ preQc, const float* __restrict__ preQp,
    const float* __restrict__ cWhh, const float* __restrict__ pWih,
    const float* __restrict__ cbhh, const float* __restrict__ pbih,
    const float* __restrict__ attnW,
    const float* __restrict__ Wr0, const float* __restrict__ Wr1,
    unsigned* __restrict__ Mbuf, unsigned* __restrict__ hxch,
    float* __restrict__ Vh, int* __restrict__ bar, const int with_lstm,
    const float* __restrict__ gi, const float* __restrict__ lstm_Whh,
    const float* __restrict__ lstm_bhh, float* __restrict__ lstm_hbuf,
    float* __restrict__ lstm_out, const unsigned seq0)
{
    __shared__ __align__(16) unsigned char smemc[40448];
    unsigned short* MbU = (unsigned short*)smemc;        // 16x520 bf16
    float* wkL  = (float*)(smemc + 16640);               // 512
    float* eh   = (float*)(smemc + 18688);               // 16x128
    float* wsf  = (float*)(smemc + 26880);               // 16x128
    float* gg   = (float*)(smemc + 35072);               // 16x48
    float* vcur = (float*)(smemc + 38144);               // 16x16
    float* invZ = (float*)(smemc + 40192);               // 16

    const int wg = blockIdx.x, tid = threadIdx.x;

    if (wg >= 128) {
        // =========================== LSTM ================================
        if (!with_lstm) return;
        float* Msf = (float*)smemc;                      // 16x520 fp32
        float* lgg = (float*)(smemc + 33280);            // 512 fp32
        const int lw = wg - 128;
        const int lp = lw >> 6;
        const int wc = lw & 63;
        unsigned* lf = (unsigned*)bar + (2 + lp) * 64;
        const int row0 = lp * 64;
        const int u = tid & 15, rr = tid >> 4;
        const int jc = u & 7, gp = u >> 3;
        const int ghid = wc * 8 + jc;
        const float* wA = lstm_Whh + (size_t)((2 * gp) * 512 + ghid) * 512;
        const float* wB = lstm_Whh + (size_t)((2 * gp + 1) * 512 + ghid) * 512;
        const float bA = lstm_bhh[(2 * gp) * 512 + ghid];
        const float bB = lstm_bhh[(2 * gp + 1) * 512 + ghid];
        float c4[4] = {0.f, 0.f, 0.f, 0.f};
        for (int t = 0; t < 32; ++t) {
            const int par = t & 1;
            for (int rc = 0; rc < 4; ++rc) {
                if (t > 0) {
                    const float* hsrc = lstm_hbuf + (size_t)par * 65536
                                      + (size_t)(row0 + rc * 16) * 512;
                    for (int s = tid; s < 8192; s += 256)
                        Msf[(s >> 9) * 520 + (s & 511)] =
                            ldc(hsrc + (size_t)(s >> 9) * 512 + (s & 511));
                }
                __syncthreads();
                const int grow = row0 + rc * 16 + rr;
                const float* gir = gi + ((size_t)t * 128 + grow) * 2048;
                float sA = bA + gir[(2 * gp) * 512 + ghid];
                float sB = bB + gir[(2 * gp + 1) * 512 + ghid];
                if (t > 0) {
                    const float* hr = Msf + rr * 520;
                    for (int k = 0; k < 512; k += 4) {
                        const float4 h4 = *(const float4*)(hr + k);
                        const float4 a4 = *(const float4*)(wA + k);
                        const float4 b4 = *(const float4*)(wB + k);
                        sA += h4.x*a4.x + h4.y*a4.y + h4.z*a4.z + h4.w*a4.w;
                        sB += h4.x*b4.x + h4.y*b4.y + h4.z*b4.z + h4.w*b4.w;
                    }
                }
                lgg[rr * 32 + jc * 4 + 2 * gp]     = sA;
                lgg[rr * 32 + jc * 4 + 2 * gp + 1] = sB;
                __syncthreads();
                if (tid < 128) {
                    const int r2 = tid >> 3, j2 = tid & 7;
                    const int grw = row0 + rc * 16 + r2;
                    const int gh2 = wc * 8 + j2;
                    const float si = lgg[r2 * 32 + j2 * 4 + 0];
                    const float sf = lgg[r2 * 32 + j2 * 4 + 1];
                    const float sg = lgg[r2 * 32 + j2 * 4 + 2];
                    const float so = lgg[r2 * 32 + j2 * 4 + 3];
                    const float c = sigf(sf) * c4[rc] + sigf(si) * tanhf(sg);
                    c4[rc] = c;
                    const float h = sigf(so) * tanhf(c);
                    stc(lstm_hbuf + (size_t)(1 - par) * 65536 + (size_t)grw * 512 + gh2, h);
                    lstm_out[((size_t)t * 128 + grw) * 512 + gh2] = h;
                }
                __syncthreads();
            }
            podsig(lf, wc, (unsigned)(t + 1));
        }
        return;
    }

    // ============================= GNN ==================================
    const int pod = wg >> 6, w = wg & 63;
    unsigned* pf = (unsigned*)bar + pod * 64;
    const int b0 = pod * 16, j0 = w * 8;
    const int wv = tid >> 6, lane = tid & 63;
    const int nI = lane & 15, quad = lane >> 4;
    unsigned* MbP = Mbuf + pod * 4096;   // [16][256] bf16-pair dwords
    unsigned* hxP = hxch + pod * 4096;
    float* VhW = Vh + (size_t)wg * 32768;  // [16][128][16]

    for (int s = tid; s < 512; s += 256) wkL[s] = attnW[512 + s];

    // ---- B fragments (hi/lo bf16 split), loaded ONCE into VGPRs ----
    const float* wrow;
    if (wv < 3) {
        const int c = (2 * wv + (nI >> 3)) * 512 + j0 + (nI & 7);
        wrow = (c < 1536) ? cWhh + (size_t)c * 512 : pWih + (size_t)(c - 1536) * 512;
    } else {
        wrow = ((nI >> 3) ? Wr1 : Wr0) + (size_t)(j0 + (nI & 7)) * 512;
    }
    s16x8 Bhi[16], Blo[16];
    #pragma unroll
    for (int kk = 0; kk < 16; ++kk) {
        const float* wp = wrow + kk * 32 + quad * 8;
        s16x8 hi, lo;
        #pragma unroll
        for (int e = 0; e < 8; ++e) {
            const float x = wp[e];
            const unsigned short hb = f2bf(x);
            hi[e] = (short)hb;
            lo[e] = (short)f2bf(x - bf2f(hb));
        }
        Bhi[kk] = hi; Blo[kk] = lo;
    }
    // combine-thread constants (6 gate biases for (b=tid>>3, jc=tid&7))
    const int cb_b = tid >> 3, cb_j = tid & 7;
    float gbias[6];
    if (tid < 128) {
        #pragma unroll
        for (int g = 0; g < 6; ++g) {
            const int c = g * 512 + j0 + cb_j;
            gbias[g] = (c < 1536) ? cbhh[c] : pbih[c - 1536];
        }
    }
    // zero M(0)
    if (w * 256 + tid < 4096) stcu(MbP + w * 256 + tid, 0u);
    podsig(pf, w, seq0 + 1);

    for (int i = 0; i < 128; ++i) {
        // ---------------- Phase 1: stage M, gate MFMA, combine h ---------
        for (int s = tid; s < 4096; s += 256) {
            const unsigned d = ldcu(MbP + s);
            *(unsigned*)(MbU + (s >> 8) * 520 + ((s & 255) << 1)) = d;
        }
        __syncthreads();
        if (wv < 3) {
            f32x4 acc = {0.f, 0.f, 0.f, 0.f};
            const unsigned short* ab = MbU + nI * 520 + quad * 8;
            #pragma unroll
            for (int kk = 0; kk < 16; ++kk) {
                const s16x8 a = *(const s16x8*)(ab + kk * 32);
                acc = __builtin_amdgcn_mfma_f32_16x16x32_bf16(a, Bhi[kk], acc, 0, 0, 0);
                acc = __builtin_amdgcn_mfma_f32_16x16x32_bf16(a, Blo[kk], acc, 0, 0, 0);
            }
            #pragma unroll
            for (int r = 0; r < 4; ++r)
                gg[(quad * 4 + r) * 48 + wv * 16 + nI] = acc[r];
        }
        __syncthreads();
        if (tid < 128) {
            const int b = cb_b, jc = cb_j, j = j0 + jc, bg = b0 + b;
            const float g0v = gg[b * 48 +  0 + jc] + gbias[0];
            const float g1v = gg[b * 48 +  8 + jc] + gbias[1];
            const float g2v = gg[b * 48 + 16 + jc] + gbias[2];
            const float g3v = gg[b * 48 + 24 + jc] + gbias[3];
            const float g4v = gg[b * 48 + 32 + jc] + gbias[4];
            const float g5v = gg[b * 48 + 40 + jc] + gbias[5];
            const float mv = bf2f(MbU[b * 520 + j]);
            const float* pc = preQc + ((size_t)bg * 128 + i) * 1536;
            const float* pp = preQp + ((size_t)bg * 128 + i) * 1536;
            const float qv = Hin[((size_t)bg * 128 + i) * 512 + j];
            const float rc = sigf(pc[j] + g0v);
            const float zc = sigf(pc[512 + j] + g1v);
            const float nc = tanhf(pc[1024 + j] + rc * g2v);
            const float oc = (1.f - zc) * nc + zc * mv;
            const float rp = sigf(g3v + pp[j]);
            const float zp = sigf(g4v + pp[512 + j]);
            const float np = tanhf(g5v + rp * pp[1024 + j]);
            const float op = (1.f - zp) * np + zp * qv;
            const float h = oc + op;
            Hout[((size_t)bg * 128 + i) * 512 + j] = h;
            if (i < 127) {
                // fused bf16-pair pack via lane shuffle (partner jc^1)
                const float hN = __shfl_xor(h, 1);
                if ((jc & 1) == 0) {
                    const unsigned d = (unsigned)f2bf(h)
                                     | ((unsigned)f2bf(hN) << 16);
                    stcu(hxP + b * 256 + (j0 >> 1) + (jc >> 1), d);
                }
            }
        }
        if (i == 127) break;   // h(127) written to Hout; nothing downstream
        podsig(pf, w, seq0 + 2 * i + 2);

        // ---------------- Phase 2: stage h, V MFMA, hk, softmax, M' ------
        for (int s = tid; s < 4096; s += 256) {
            const unsigned d = ldcu(hxP + s);
            *(unsigned*)(MbU + (s >> 8) * 520 + ((s & 255) << 1)) = d;
        }
        __syncthreads();
        if (wv == 3) {
            f32x4 acc = {0.f, 0.f, 0.f, 0.f};
            const unsigned short* ab = MbU + nI * 520 + quad * 8;
            #pragma unroll
            for (int kk = 0; kk < 16; ++kk) {
                const s16x8 a = *(const s16x8*)(ab + kk * 32);
                acc = __builtin_amdgcn_mfma_f32_16x16x32_bf16(a, Bhi[kk], acc, 0, 0, 0);
                acc = __builtin_amdgcn_mfma_f32_16x16x32_bf16(a, Blo[kk], acc, 0, 0, 0);
            }
            #pragma unroll
            for (int r = 0; r < 4; ++r) {
                const int b = quad * 4 + r;
                vcur[b * 16 + nI] = acc[r];
                VhW[((size_t)b * 128 + i) * 16 + nI] = acc[r];
            }
        }
        {   // hk partials (lane-contiguous) + width-16 shuffle reduce
            const int bq = tid >> 4, u = tid & 15;
            const unsigned short* hr = MbU + bq * 520;
            float p = 0.f;
            #pragma unroll
            for (int kk = 0; kk < 32; ++kk) {
                const int k = u + kk * 16;
                p += bf2f(hr[k]) * wkL[k];
            }
            #pragma unroll
            for (int off = 8; off > 0; off >>= 1) p += __shfl_xor(p, off, 16);
            if (u == 0) eh[bq * 128 + i] = p;
        }
        __syncthreads();
        {
            const int bq = tid >> 4, u = tid & 15;
            const float* arow = adj + ((size_t)(b0 + bq) * 128 + (i + 1)) * 128;
            float amx = -3.0e38f;
            for (int n = u; n <= i; n += 16)
                amx = fmaxf(amx, eh[bq * 128 + n] - (1.f - arow[n]) * 1e30f);
            #pragma unroll
            for (int off = 8; off > 0; off >>= 1)
                amx = fmaxf(amx, __shfl_xor(amx, off, 16));
            float es = 0.f;
            for (int n = u; n <= i; n += 16) {
                const float e = __expf(eh[bq * 128 + n] - (1.f - arow[n]) * 1e30f - amx);
                wsf[bq * 128 + n] = e;
                es += e;
            }
            #pragma unroll
            for (int off = 8; off > 0; off >>= 1) es += __shfl_xor(es, off, 16);
            if (u == 0) invZ[bq] = 1.f / es;
        }
        __syncthreads();
        if (tid < 128) {
            const int b = cb_b, jc = cb_j;
            const float* srow = smk + ((size_t)(b0 + b) * 128 + (i + 1)) * 128;
            const float* vb = VhW + (size_t)b * 128 * 16;
            float acc2 = 0.f;
            for (int n = 0; n < i; ++n) {
                const float wgt = wsf[b * 128 + n];
                acc2 += wgt * ((srow[n] != 0.f) ? vb[n * 16 + jc] : vb[n * 16 + 8 + jc]);
            }
            acc2 += wsf[b * 128 + i] *
                    ((srow[i] != 0.f) ? vcur[b * 16 + jc] : vcur[b * 16 + 8 + jc]);
            const float mval = acc2 * invZ[b];
            // fused bf16-pair pack via lane shuffle (partner jc^1)
            const float mN = __shfl_xor(mval, 1);
            if ((jc & 1) == 0) {
                const unsigned d = (unsigned)f2bf(mval)
                                 | ((unsigned)f2bf(mN) << 16);
                stcu(MbP + b * 256 + (j0 >> 1) + (jc >> 1), d);
            }
        }
        podsig(pf, w, seq0 + 2 * i + 3);
    }
}

// ---------------------------------------------------------------------------
__global__ __launch_bounds__(256) void out_gemm(
    const float* __restrict__ x2, const float* __restrict__ W,
    const float* __restrict__ bias, float* __restrict__ out)
{
    __shared__ float xs[16 * 516];
    const int tid = threadIdx.x;
    const int r0 = blockIdx.x * 16;
    for (int idx = tid; idx < 16 * 512; idx += 256) {
        const int rr = idx >> 9, kk = idx & 511;
        xs[rr * 516 + kk] = x2[(size_t)(r0 + rr) * 512 + kk];
    }
    __syncthreads();
    if (tid < 128) {
        const int r = tid >> 3, c = tid & 7;
        if (c < 7) {
            float acc = bias[c];
            const float* wr = W + c * 512;
            const float* xr = xs + r * 516;
            for (int k = 0; k < 512; ++k) acc += xr[k] * wr[k];
            out[(size_t)(r0 + r) * 7 + c] = acc;
        }
    }
}

// ---------------------------------------------------------------------------
extern "C" void kernel_launch(void* const* d_in, const int* in_sizes, int n_in,
                              void* d_out, int out_size, void* d_ws, size_t ws_size,
                              hipStream_t stream) {
    (void)in_sizes; (void)n_in; (void)out_size; (void)ws_size;
    const float* feat     = (const float*)d_in[0];
    const float* adj      = (const float*)d_in[1];
    const float* smask    = (const float*)d_in[2];
    const float* lstm_Wih = (const float*)d_in[5];
    const float* lstm_Whh = (const float*)d_in[6];
    const float* lstm_bih = (const float*)d_in[7];
    const float* lstm_bhh = (const float*)d_in[8];
    const float* fc1_W    = (const float*)d_in[9];
    const float* fc1_b    = (const float*)d_in[10];
    const float* attn_W   = (const float*)d_in[11];
    const float* Wr0      = (const float*)d_in[13];
    const float* Wr1      = (const float*)d_in[14];
    const float* gruC_Wih = (const float*)d_in[15];
    const float* gruC_Whh = (const float*)d_in[16];
    const float* gruC_bih = (const float*)d_in[17];
    const float* gruC_bhh = (const float*)d_in[18];
    const float* gruP_Wih = (const float*)d_in[19];
    const float* gruP_Whh = (const float*)d_in[20];
    const float* gruP_bih = (const float*)d_in[21];
    const float* gruP_bhh = (const float*)d_in[22];
    const float* mlp0_W   = (const float*)d_in[23];
    const float* mlp0_b   = (const float*)d_in[24];
    const float* mlp1_W   = (const float*)d_in[25];
    const float* mlp1_b   = (const float*)d_in[26];
    const float* out_W    = (const float*)d_in[27];
    const float* out_b    = (const float*)d_in[28];

    float* ws       = (float*)d_ws;
    float* lstm_gi  = ws;                        // 8,388,608
    float* lstm_out = lstm_gi + 8388608;         // 2,097,152
    float* H0       = lstm_out + 2097152;        // 2,097,152
    float* H1       = H0 + 2097152;              // 2,097,152
    float* H2       = H1 + 2097152;              // 2,097,152
    float* preQc    = H2 + 2097152;              // 6,291,456
    float* preQp    = preQc + 6291456;           // 6,291,456
    float* x1       = preQp + 6291456;           // 2,097,152
    float* x2       = x1 + 2097152;              // 2,097,152
    unsigned* Mbuf  = (unsigned*)(x2 + 2097152); // 8,192 dwords
    unsigned* hxch  = Mbuf + 8192;               // 8,192 dwords
    float* Vh       = (float*)(hxch + 8192);     // 4,194,304
    float* lstm_hb  = Vh + 4194304;              // 131,072
    int*   bar      = (int*)(lstm_hb + 131072);  // 1,024 ints

    const dim3 blk(256);
    init_bar<<<1, 1024, 0, stream>>>(bar);

    // parallel-phase GEMMs
    gemm_nt<<<dim3(64, 8), blk, 0, stream>>>(feat, fc1_W, fc1_b, H0, 4096, 512, 1024, 1);
    gemm_nt<<<dim3(64, 32), blk, 0, stream>>>(feat, lstm_Wih, lstm_bih, lstm_gi, 4096, 2048, 1024, 0);
    gemm_nt<<<dim3(64, 24), blk, 0, stream>>>(H0, gruC_Wih, gruC_bih, preQc, 4096, 1536, 512, 0);
    gemm_nt<<<dim3(64, 24), blk, 0, stream>>>(H0, gruP_Whh, gruP_bhh, preQp, 4096, 1536, 512, 0);

    // layer 0 scan (+ LSTM on WGs 128..255); GNN flags end at seq 255
    scan_layer<<<256, blk, 0, stream>>>(
        H0, H1, adj, smask, preQc, preQp,
        gruC_Whh, gruP_Wih, gruC_bhh, gruP_bih, attn_W,
        Wr0, Wr1, Mbuf, hxch, Vh, bar, 1,
        lstm_gi, lstm_Whh, lstm_bhh, lstm_hb, lstm_out, 0u);

    // layer-1 preQ
    gemm_nt<<<dim3(64, 24), blk, 0, stream>>>(H1, gruC_Wih + (size_t)1536 * 512,
                                              gruC_bih + 1536, preQc, 4096, 1536, 512, 0);
    gemm_nt<<<dim3(64, 24), blk, 0, stream>>>(H1, gruP_Whh + (size_t)1536 * 512,
                                              gruP_bhh + 1536, preQp, 4096, 1536, 512, 0);

    // layer 1 scan (GNN only, 128 WGs); seq continues from layer 0's 255
    scan_layer<<<128, blk, 0, stream>>>(
        H1, H2, adj, smask, preQc, preQp,
        gruC_Whh + (size_t)1536 * 512, gruP_Wih + (size_t)1536 * 512,
        gruC_bhh + 1536, gruP_bih + 1536, attn_W + 1024,
        Wr0 + (size_t)512 * 512, Wr1 + (size_t)512 * 512,
        Mbuf, hxch, Vh, bar, 0,
        lstm_gi, lstm_Whh, lstm_bhh, lstm_hb, lstm_out, 255u);

    // head
    gemm_cat<<<dim3(64, 8), blk, 0, stream>>>(H0, H1, H2, feat, lstm_out, mlp0_W, mlp0_b, x1);
    gemm_nt<<<dim3(64, 8), blk, 0, stream>>>(x1, mlp1_W, mlp1_b, x2, 4096, 512, 512, 1);
    out_gemm<<<256, blk, 0, stream>>>(x2, out_W, out_b, (float*)d_out);
}

// Round 4
// 8356.241 us; speedup vs baseline: 1.0258x; 1.0258x over previous
//
#include <hip/hip_runtime.h>
#include <math.h>

// Sizes: B=32, N=128, EMB=1024, HID=512, L=2, NCLS=7, IN_DIM=3072, TOK=4096
// Scan: weight-stationary MFMA. 2 GNN pods x 64 WGs x 16 batches. Each WG
// owns 8 h-cols; waves 0-2 hold gate-weight tiles (6 gates x 8 cols) and
// wave 3 holds the V tile ({Wr0|Wr1} 8+8 cols) as bf16 hi/lo B-fragments in
// VGPRs (loaded once). Per step: stage M (bf16) -> 32 MFMAs -> gates/h local
// -> exchange h -> stage h -> V MFMA + hk + softmax + M'. V history lives in
// LDS (bf16, 113KB total static LDS -> 1 WG/CU) so the M' weighted sum runs
// on LDS instead of serial global loads. wsf/eh stride 132 and gg stride 50
// kill the 16-way/8-way bank conflicts in the hot loops. Cross-WG sync is a
// store-flag barrier. LSTM on WGs 128..255 (layer-0 launch).

typedef __attribute__((ext_vector_type(4))) float f32x4;
typedef __attribute__((ext_vector_type(8))) short s16x8;

#define AGENT __HIP_MEMORY_SCOPE_AGENT

__device__ __forceinline__ float ldc(const float* p) {
    return __hip_atomic_load(p, __ATOMIC_RELAXED, AGENT);
}
__device__ __forceinline__ void stc(float* p, float v) {
    __hip_atomic_store(p, v, __ATOMIC_RELAXED, AGENT);
}
__device__ __forceinline__ unsigned ldcu(const unsigned* p) {
    return __hip_atomic_load(p, __ATOMIC_RELAXED, AGENT);
}
__device__ __forceinline__ void stcu(unsigned* p, unsigned v) {
    __hip_atomic_store(p, v, __ATOMIC_RELAXED, AGENT);
}

// Store-flag pod barrier. All 64 WGs of a pod call with the same monotonic
// seq. Entry __syncthreads drains each thread's outstanding stores; the
// s_waitcnt(0) drains the flag-writer. Wave 0 polls all 64 flags (one
// coalesced 256B agent load per iteration).
__device__ __forceinline__ void podsig(unsigned* flags, int w, unsigned seq) {
    __syncthreads();
    if (threadIdx.x == 0) {
        __builtin_amdgcn_s_waitcnt(0);
        stcu(flags + w, seq);
    }
    if (threadIdx.x < 64) {
        while (ldcu(flags + threadIdx.x) < seq) {
            __builtin_amdgcn_s_sleep(1);
        }
    }
    __asm__ __volatile__("" ::: "memory");
    __syncthreads();
}

__global__ void init_bar(int* bar) { bar[threadIdx.x] = 0; }

__device__ __forceinline__ float sigf(float x) { return 1.f / (1.f + __expf(-x)); }

// fp32 -> bf16 (RNE) and back
__device__ __forceinline__ unsigned short f2bf(float f) {
    unsigned u = __float_as_uint(f);
    return (unsigned short)((u + 0x7fffu + ((u >> 16) & 1u)) >> 16);
}
__device__ __forceinline__ float bf2f(unsigned short h) {
    return __uint_as_float(((unsigned)h) << 16);
}

// ---------------------------------------------------------------------------
// Generic fp32 GEMM: C = act(A[M,K] @ W[N,K]^T + bias). 64x64 tile.
// ---------------------------------------------------------------------------
__global__ __launch_bounds__(256) void gemm_nt(
    const float* __restrict__ A, const float* __restrict__ W,
    const float* __restrict__ bias, float* __restrict__ C,
    int M, int N, int K, int relu)
{
    __shared__ float As[16][68];
    __shared__ float Ws[16][68];
    const int tid = threadIdx.x;
    const int m0 = blockIdx.x * 64;
    const int n0 = blockIdx.y * 64;
    const int lr = tid >> 2;
    const int lk = (tid & 3) << 2;
    const int tm = (tid & 15) << 2;
    const int tn = (tid >> 4) << 2;
    float acc[4][4] = {};
    const float* Aptr = A + (size_t)(m0 + lr) * K + lk;
    const float* Wptr = W + (size_t)(n0 + lr) * K + lk;
    for (int k0 = 0; k0 < K; k0 += 16) {
        __syncthreads();
        const float4 av = *(const float4*)(Aptr + k0);
        const float4 wv = *(const float4*)(Wptr + k0);
        As[lk + 0][lr] = av.x; As[lk + 1][lr] = av.y;
        As[lk + 2][lr] = av.z; As[lk + 3][lr] = av.w;
        Ws[lk + 0][lr] = wv.x; Ws[lk + 1][lr] = wv.y;
        Ws[lk + 2][lr] = wv.z; Ws[lk + 3][lr] = wv.w;
        __syncthreads();
        #pragma unroll
        for (int kk = 0; kk < 16; ++kk) {
            float a[4], b[4];
            #pragma unroll
            for (int u = 0; u < 4; ++u) { a[u] = As[kk][tm + u]; b[u] = Ws[kk][tn + u]; }
            #pragma unroll
            for (int ii = 0; ii < 4; ++ii)
                #pragma unroll
                for (int jj = 0; jj < 4; ++jj)
                    acc[ii][jj] += a[ii] * b[jj];
        }
    }
    #pragma unroll
    for (int ii = 0; ii < 4; ++ii)
        #pragma unroll
        for (int jj = 0; jj < 4; ++jj) {
            float v = acc[ii][jj] + bias[n0 + tn + jj];
            if (relu) v = fmaxf(v, 0.f);
            C[(size_t)(m0 + tm + ii) * N + n0 + tn + jj] = v;
        }
}

// ---------------------------------------------------------------------------
// mlp0 with fused 5-way concat
// ---------------------------------------------------------------------------
__global__ __launch_bounds__(256) void gemm_cat(
    const float* __restrict__ H0, const float* __restrict__ H1,
    const float* __restrict__ H2, const float* __restrict__ feat,
    const float* __restrict__ lstm, const float* __restrict__ W,
    const float* __restrict__ bias, float* __restrict__ C)
{
    __shared__ float As[16][68];
    __shared__ float Ws[16][68];
    const int tid = threadIdx.x;
    const int m0 = blockIdx.x * 64;
    const int n0 = blockIdx.y * 64;
    const int lr = tid >> 2;
    const int lk = (tid & 3) << 2;
    const int tm = (tid & 15) << 2;
    const int tn = (tid >> 4) << 2;
    float acc[4][4] = {};
    for (int k0 = 0; k0 < 3072; k0 += 16) {
        const float* src; int kloc, Kp;
        if (k0 < 512)       { src = H0;   kloc = k0;        Kp = 512;  }
        else if (k0 < 1024) { src = H1;   kloc = k0 - 512;  Kp = 512;  }
        else if (k0 < 1536) { src = H2;   kloc = k0 - 1024; Kp = 512;  }
        else if (k0 < 2560) { src = feat; kloc = k0 - 1536; Kp = 1024; }
        else                { src = lstm; kloc = k0 - 2560; Kp = 512;  }
        __syncthreads();
        const float4 av = *(const float4*)(src + (size_t)(m0 + lr) * Kp + kloc + lk);
        const float4 wv = *(const float4*)(W + (size_t)(n0 + lr) * 3072 + k0 + lk);
        As[lk + 0][lr] = av.x; As[lk + 1][lr] = av.y;
        As[lk + 2][lr] = av.z; As[lk + 3][lr] = av.w;
        Ws[lk + 0][lr] = wv.x; Ws[lk + 1][lr] = wv.y;
        Ws[lk + 2][lr] = wv.z; Ws[lk + 3][lr] = wv.w;
        __syncthreads();
        #pragma unroll
        for (int kk = 0; kk < 16; ++kk) {
            float a[4], b[4];
            #pragma unroll
            for (int u = 0; u < 4; ++u) { a[u] = As[kk][tm + u]; b[u] = Ws[kk][tn + u]; }
            #pragma unroll
            for (int ii = 0; ii < 4; ++ii)
                #pragma unroll
                for (int jj = 0; jj < 4; ++jj)
                    acc[ii][jj] += a[ii] * b[jj];
        }
    }
    #pragma unroll
    for (int ii = 0; ii < 4; ++ii)
        #pragma unroll
        for (int jj = 0; jj < 4; ++jj) {
            float v = fmaxf(acc[ii][jj] + bias[n0 + tn + jj], 0.f);
            C[(size_t)(m0 + tm + ii) * 512 + n0 + tn + jj] = v;
        }
}

// ---------------------------------------------------------------------------
// One GNN layer scan (weight-stationary MFMA). Grid 256 (layer 0) / 128.
// LDS map (GNN):            bytes       LDS map (LSTM overlay):
//   MbU   16x520 bf16      0..16640       Msf 16x520 f32  0..33280
//   wkL   512 f32      16640..18688       lgg 512 f32 33280..35328
//   eh    16x132 f32   18688..27136
//   wsf   16x132 f32   27136..35584
//   gg    16x50  f32   35584..38784
//   invZ  16 f32       38784..38848
//   smkr  16x132 f32   38848..47296
//   VhL   16x2056 bf16 47296..112880   (slab = 128*16 + 8 pad elems)
// ---------------------------------------------------------------------------
__global__ __launch_bounds__(256, 1) void scan_layer(
    const float* __restrict__ Hin, float* __restrict__ Hout,
    const float* __restrict__ adj, const float* __restrict__ smk,
    const float* __restrict__ preQc, const float* __restrict__ preQp,
    const float* __restrict__ cWhh, const float* __restrict__ pWih,
    const float* __restrict__ cbhh, const float* __restrict__ pbih,
    const float* __restrict__ attnW,
    const float* __restrict__ Wr0, const float* __restrict__ Wr1,
    unsigned* __restrict__ Mbuf, unsigned* __restrict__ hxch,
    float* __restrict__ Vh, int* __restrict__ bar, const int with_lstm,
    const float* __restrict__ gi, const float* __restrict__ lstm_Whh,
    const float* __restrict__ lstm_bhh, float* __restrict__ lstm_hbuf,
    float* __restrict__ lstm_out, const unsigned seq0)
{
    __shared__ __align__(16) unsigned char smemc[112880];
    unsigned short* MbU = (unsigned short*)smemc;           // 16x520 bf16
    float* wkL  = (float*)(smemc + 16640);                  // 512
    float* eh   = (float*)(smemc + 18688);                  // 16x132
    float* wsf  = (float*)(smemc + 27136);                  // 16x132
    float* gg   = (float*)(smemc + 35584);                  // 16x50
    float* invZ = (float*)(smemc + 38784);                  // 16
    float* smkr = (float*)(smemc + 38848);                  // 16x132
    unsigned short* VhL = (unsigned short*)(smemc + 47296); // 16x(128*16+8)
    (void)Vh;

    const int wg = blockIdx.x, tid = threadIdx.x;

    if (wg >= 128) {
        // =========================== LSTM ================================
        if (!with_lstm) return;
        float* Msf = (float*)smemc;                      // 16x520 fp32
        float* lgg = (float*)(smemc + 33280);            // 512 fp32
        const int lw = wg - 128;
        const int lp = lw >> 6;
        const int wc = lw & 63;
        unsigned* lf = (unsigned*)bar + (2 + lp) * 64;
        const int row0 = lp * 64;
        const int u = tid & 15, rr = tid >> 4;
        const int jc = u & 7, gp = u >> 3;
        const int ghid = wc * 8 + jc;
        const float* wA = lstm_Whh + (size_t)((2 * gp) * 512 + ghid) * 512;
        const float* wB = lstm_Whh + (size_t)((2 * gp + 1) * 512 + ghid) * 512;
        const float bA = lstm_bhh[(2 * gp) * 512 + ghid];
        const float bB = lstm_bhh[(2 * gp + 1) * 512 + ghid];
        float c4[4] = {0.f, 0.f, 0.f, 0.f};
        for (int t = 0; t < 32; ++t) {
            const int par = t & 1;
            for (int rc = 0; rc < 4; ++rc) {
                if (t > 0) {
                    const float* hsrc = lstm_hbuf + (size_t)par * 65536
                                      + (size_t)(row0 + rc * 16) * 512;
                    for (int s = tid; s < 8192; s += 256)
                        Msf[(s >> 9) * 520 + (s & 511)] =
                            ldc(hsrc + (size_t)(s >> 9) * 512 + (s & 511));
                }
                __syncthreads();
                const int grow = row0 + rc * 16 + rr;
                const float* gir = gi + ((size_t)t * 128 + grow) * 2048;
                float sA = bA + gir[(2 * gp) * 512 + ghid];
                float sB = bB + gir[(2 * gp + 1) * 512 + ghid];
                if (t > 0) {
                    const float* hr = Msf + rr * 520;
                    for (int k = 0; k < 512; k += 4) {
                        const float4 h4 = *(const float4*)(hr + k);
                        const float4 a4 = *(const float4*)(wA + k);
                        const float4 b4 = *(const float4*)(wB + k);
                        sA += h4.x*a4.x + h4.y*a4.y + h4.z*a4.z + h4.w*a4.w;
                        sB += h4.x*b4.x + h4.y*b4.y + h4.z*b4.z + h4.w*b4.w;
                    }
                }
                lgg[rr * 32 + jc * 4 + 2 * gp]     = sA;
                lgg[rr * 32 + jc * 4 + 2 * gp + 1] = sB;
                __syncthreads();
                if (tid < 128) {
                    const int r2 = tid >> 3, j2 = tid & 7;
                    const int grw = row0 + rc * 16 + r2;
                    const int gh2 = wc * 8 + j2;
                    const float si = lgg[r2 * 32 + j2 * 4 + 0];
                    const float sf = lgg[r2 * 32 + j2 * 4 + 1];
                    const float sg = lgg[r2 * 32 + j2 * 4 + 2];
                    const float so = lgg[r2 * 32 + j2 * 4 + 3];
                    const float c = sigf(sf) * c4[rc] + sigf(si) * tanhf(sg);
                    c4[rc] = c;
                    const float h = sigf(so) * tanhf(c);
                    stc(lstm_hbuf + (size_t)(1 - par) * 65536 + (size_t)grw * 512 + gh2, h);
                    lstm_out[((size_t)t * 128 + grw) * 512 + gh2] = h;
                }
                __syncthreads();
            }
            podsig(lf, wc, (unsigned)(t + 1));
        }
        return;
    }

    // ============================= GNN ==================================
    const int pod = wg >> 6, w = wg & 63;
    unsigned* pf = (unsigned*)bar + pod * 64;
    const int b0 = pod * 16, j0 = w * 8;
    const int wv = tid >> 6, lane = tid & 63;
    const int nI = lane & 15, quad = lane >> 4;
    unsigned* MbP = Mbuf + pod * 4096;   // [16][256] bf16-pair dwords
    unsigned* hxP = hxch + pod * 4096;

    for (int s = tid; s < 512; s += 256) wkL[s] = attnW[512 + s];

    // ---- B fragments (hi/lo bf16 split), loaded ONCE into VGPRs ----
    const float* wrow;
    if (wv < 3) {
        const int c = (2 * wv + (nI >> 3)) * 512 + j0 + (nI & 7);
        wrow = (c < 1536) ? cWhh + (size_t)c * 512 : pWih + (size_t)(c - 1536) * 512;
    } else {
        wrow = ((nI >> 3) ? Wr1 : Wr0) + (size_t)(j0 + (nI & 7)) * 512;
    }
    s16x8 Bhi[16], Blo[16];
    #pragma unroll
    for (int kk = 0; kk < 16; ++kk) {
        const float* wp = wrow + kk * 32 + quad * 8;
        s16x8 hi, lo;
        #pragma unroll
        for (int e = 0; e < 8; ++e) {
            const float x = wp[e];
            const unsigned short hb = f2bf(x);
            hi[e] = (short)hb;
            lo[e] = (short)f2bf(x - bf2f(hb));
        }
        Bhi[kk] = hi; Blo[kk] = lo;
    }
    // combine-thread constants (6 gate biases for (b=tid>>3, jc=tid&7))
    const int cb_b = tid >> 3, cb_j = tid & 7;
    float gbias[6];
    if (tid < 128) {
        #pragma unroll
        for (int g = 0; g < 6; ++g) {
            const int c = g * 512 + j0 + cb_j;
            gbias[g] = (c < 1536) ? cbhh[c] : pbih[c - 1536];
        }
    }
    // zero M(0)
    if (w * 256 + tid < 4096) stcu(MbP + w * 256 + tid, 0u);
    podsig(pf, w, seq0 + 1);

    for (int i = 0; i < 128; ++i) {
        // ---------------- Phase 1: stage M, gate MFMA, combine h ---------
        for (int s = tid; s < 4096; s += 256) {
            const unsigned d = ldcu(MbP + s);
            *(unsigned*)(MbU + (s >> 8) * 520 + ((s & 255) << 1)) = d;
        }
        __syncthreads();
        if (wv < 3) {
            f32x4 acc = {0.f, 0.f, 0.f, 0.f};
            const unsigned short* ab = MbU + nI * 520 + quad * 8;
            #pragma unroll
            for (int kk = 0; kk < 16; ++kk) {
                const s16x8 a = *(const s16x8*)(ab + kk * 32);
                acc = __builtin_amdgcn_mfma_f32_16x16x32_bf16(a, Bhi[kk], acc, 0, 0, 0);
                acc = __builtin_amdgcn_mfma_f32_16x16x32_bf16(a, Blo[kk], acc, 0, 0, 0);
            }
            #pragma unroll
            for (int r = 0; r < 4; ++r)
                gg[(quad * 4 + r) * 50 + wv * 16 + nI] = acc[r];
        }
        __syncthreads();
        if (tid < 128) {
            const int b = cb_b, jc = cb_j, j = j0 + jc, bg = b0 + b;
            const float g0v = gg[b * 50 +  0 + jc] + gbias[0];
            const float g1v = gg[b * 50 +  8 + jc] + gbias[1];
            const float g2v = gg[b * 50 + 16 + jc] + gbias[2];
            const float g3v = gg[b * 50 + 24 + jc] + gbias[3];
            const float g4v = gg[b * 50 + 32 + jc] + gbias[4];
            const float g5v = gg[b * 50 + 40 + jc] + gbias[5];
            const float mv = bf2f(MbU[b * 520 + j]);
            const float* pc = preQc + ((size_t)bg * 128 + i) * 1536;
            const float* pp = preQp + ((size_t)bg * 128 + i) * 1536;
            const float qv = Hin[((size_t)bg * 128 + i) * 512 + j];
            const float rc = sigf(pc[j] + g0v);
            const float zc = sigf(pc[512 + j] + g1v);
            const float nc = tanhf(pc[1024 + j] + rc * g2v);
            const float oc = (1.f - zc) * nc + zc * mv;
            const float rp = sigf(g3v + pp[j]);
            const float zp = sigf(g4v + pp[512 + j]);
            const float np = tanhf(g5v + rp * pp[1024 + j]);
            const float op = (1.f - zp) * np + zp * qv;
            const float h = oc + op;
            Hout[((size_t)bg * 128 + i) * 512 + j] = h;
            if (i < 127) {
                // fused bf16-pair pack via lane shuffle (partner jc^1)
                const float hN = __shfl_xor(h, 1);
                if ((jc & 1) == 0) {
                    const unsigned d = (unsigned)f2bf(h)
                                     | ((unsigned)f2bf(hN) << 16);
                    stcu(hxP + b * 256 + (j0 >> 1) + (jc >> 1), d);
                }
            }
        }
        if (i == 127) break;   // h(127) written to Hout; nothing downstream
        podsig(pf, w, seq0 + 2 * i + 2);

        // ---------------- Phase 2: stage h + smk row, V MFMA, hk, softmax,
        // ---------------- M' (V history in LDS) --------------------------
        for (int s = tid; s < 4096; s += 256) {
            const unsigned d = ldcu(hxP + s);
            *(unsigned*)(MbU + (s >> 8) * 520 + ((s & 255) << 1)) = d;
        }
        {   // stage s_mask row (i+1) for the pod's 16 batches
            const float* sr = smk + ((size_t)b0 * 128 + (i + 1)) * 128;
            for (int s = tid; s < 2048; s += 256)
                smkr[(s >> 7) * 132 + (s & 127)] = sr[(size_t)(s >> 7) * 16384 + (s & 127)];
        }
        __syncthreads();
        if (wv == 3) {
            f32x4 acc = {0.f, 0.f, 0.f, 0.f};
            const unsigned short* ab = MbU + nI * 520 + quad * 8;
            #pragma unroll
            for (int kk = 0; kk < 16; ++kk) {
                const s16x8 a = *(const s16x8*)(ab + kk * 32);
                acc = __builtin_amdgcn_mfma_f32_16x16x32_bf16(a, Bhi[kk], acc, 0, 0, 0);
                acc = __builtin_amdgcn_mfma_f32_16x16x32_bf16(a, Blo[kk], acc, 0, 0, 0);
            }
            #pragma unroll
            for (int r = 0; r < 4; ++r) {
                const int b = quad * 4 + r;
                VhL[b * 2056 + i * 16 + nI] = f2bf(acc[r]);
            }
        }
        {   // hk partials (lane-contiguous) + width-16 shuffle reduce
            const int bq = tid >> 4, u = tid & 15;
            const unsigned short* hr = MbU + bq * 520;
            float p = 0.f;
            #pragma unroll
            for (int kk = 0; kk < 32; ++kk) {
                const int k = u + kk * 16;
                p += bf2f(hr[k]) * wkL[k];
            }
            #pragma unroll
            for (int off = 8; off > 0; off >>= 1) p += __shfl_xor(p, off, 16);
            if (u == 0) eh[bq * 132 + i] = p;
        }
        __syncthreads();
        {
            const int bq = tid >> 4, u = tid & 15;
            const float* arow = adj + ((size_t)(b0 + bq) * 128 + (i + 1)) * 128;
            float amx = -3.0e38f;
            for (int n = u; n <= i; n += 16)
                amx = fmaxf(amx, eh[bq * 132 + n] - (1.f - arow[n]) * 1e30f);
            #pragma unroll
            for (int off = 8; off > 0; off >>= 1)
                amx = fmaxf(amx, __shfl_xor(amx, off, 16));
            float es = 0.f;
            for (int n = u; n <= i; n += 16) {
                const float e = __expf(eh[bq * 132 + n] - (1.f - arow[n]) * 1e30f - amx);
                wsf[bq * 132 + n] = e;
                es += e;
            }
            #pragma unroll
            for (int off = 8; off > 0; off >>= 1) es += __shfl_xor(es, off, 16);
            if (u == 0) invZ[bq] = 1.f / es;
        }
        __syncthreads();
        if (tid < 128) {
            const int b = cb_b, jc = cb_j;
            const float* wrow_ = wsf + b * 132;
            const float* srow_ = smkr + b * 132;
            const unsigned short* vb = VhL + b * 2056 + jc;
            float acc2 = 0.f;
            for (int n = 0; n <= i; ++n) {
                const float wgt = wrow_[n];
                const int sel = (srow_[n] != 0.f) ? 0 : 8;
                acc2 += wgt * bf2f(vb[n * 16 + sel]);
            }
            const float mval = acc2 * invZ[b];
            // fused bf16-pair pack via lane shuffle (partner jc^1)
            const float mN = __shfl_xor(mval, 1);
            if ((jc & 1) == 0) {
                const unsigned d = (unsigned)f2bf(mval)
                                 | ((unsigned)f2bf(mN) << 16);
                stcu(MbP + b * 256 + (j0 >> 1) + (jc >> 1), d);
            }
        }
        podsig(pf, w, seq0 + 2 * i + 3);
    }
}

// ---------------------------------------------------------------------------
__global__ __launch_bounds__(256) void out_gemm(
    const float* __restrict__ x2, const float* __restrict__ W,
    const float* __restrict__ bias, float* __restrict__ out)
{
    __shared__ float xs[16 * 516];
    const int tid = threadIdx.x;
    const int r0 = blockIdx.x * 16;
    for (int idx = tid; idx < 16 * 512; idx += 256) {
        const int rr = idx >> 9, kk = idx & 511;
        xs[rr * 516 + kk] = x2[(size_t)(r0 + rr) * 512 + kk];
    }
    __syncthreads();
    if (tid < 128) {
        const int r = tid >> 3, c = tid & 7;
        if (c < 7) {
            float acc = bias[c];
            const float* wr = W + c * 512;
            const float* xr = xs + r * 516;
            for (int k = 0; k < 512; ++k) acc += xr[k] * wr[k];
            out[(size_t)(r0 + r) * 7 + c] = acc;
        }
    }
}

// ---------------------------------------------------------------------------
extern "C" void kernel_launch(void* const* d_in, const int* in_sizes, int n_in,
                              void* d_out, int out_size, void* d_ws, size_t ws_size,
                              hipStream_t stream) {
    (void)in_sizes; (void)n_in; (void)out_size; (void)ws_size;
    const float* feat     = (const float*)d_in[0];
    const float* adj      = (const float*)d_in[1];
    const float* smask    = (const float*)d_in[2];
    const float* lstm_Wih = (const float*)d_in[5];
    const float* lstm_Whh = (const float*)d_in[6];
    const float* lstm_bih = (const float*)d_in[7];
    const float* lstm_bhh = (const float*)d_in[8];
    const float* fc1_W    = (const float*)d_in[9];
    const float* fc1_b    = (const float*)d_in[10];
    const float* attn_W   = (const float*)d_in[11];
    const float* Wr0      = (const float*)d_in[13];
    const float* Wr1      = (const float*)d_in[14];
    const float* gruC_Wih = (const float*)d_in[15];
    const float* gruC_Whh = (const float*)d_in[16];
    const float* gruC_bih = (const float*)d_in[17];
    const float* gruC_bhh = (const float*)d_in[18];
    const float* gruP_Wih = (const float*)d_in[19];
    const float* gruP_Whh = (const float*)d_in[20];
    const float* gruP_bih = (const float*)d_in[21];
    const float* gruP_bhh = (const float*)d_in[22];
    const float* mlp0_W   = (const float*)d_in[23];
    const float* mlp0_b   = (const float*)d_in[24];
    const float* mlp1_W   = (const float*)d_in[25];
    const float* mlp1_b   = (const float*)d_in[26];
    const float* out_W    = (const float*)d_in[27];
    const float* out_b    = (const float*)d_in[28];

    float* ws       = (float*)d_ws;
    float* lstm_gi  = ws;                        // 8,388,608
    float* lstm_out = lstm_gi + 8388608;         // 2,097,152
    float* H0       = lstm_out + 2097152;        // 2,097,152
    float* H1       = H0 + 2097152;              // 2,097,152
    float* H2       = H1 + 2097152;              // 2,097,152
    float* preQc    = H2 + 2097152;              // 6,291,456
    float* preQp    = preQc + 6291456;           // 6,291,456
    float* x1       = preQp + 6291456;           // 2,097,152
    float* x2       = x1 + 2097152;              // 2,097,152
    unsigned* Mbuf  = (unsigned*)(x2 + 2097152); // 8,192 dwords
    unsigned* hxch  = Mbuf + 8192;               // 8,192 dwords
    float* Vh       = (float*)(hxch + 8192);     // 4,194,304 (unused)
    float* lstm_hb  = Vh + 4194304;              // 131,072
    int*   bar      = (int*)(lstm_hb + 131072);  // 1,024 ints

    const dim3 blk(256);
    init_bar<<<1, 1024, 0, stream>>>(bar);

    // parallel-phase GEMMs
    gemm_nt<<<dim3(64, 8), blk, 0, stream>>>(feat, fc1_W, fc1_b, H0, 4096, 512, 1024, 1);
    gemm_nt<<<dim3(64, 32), blk, 0, stream>>>(feat, lstm_Wih, lstm_bih, lstm_gi, 4096, 2048, 1024, 0);
    gemm_nt<<<dim3(64, 24), blk, 0, stream>>>(H0, gruC_Wih, gruC_bih, preQc, 4096, 1536, 512, 0);
    gemm_nt<<<dim3(64, 24), blk, 0, stream>>>(H0, gruP_Whh, gruP_bhh, preQp, 4096, 1536, 512, 0);

    // layer 0 scan (+ LSTM on WGs 128..255); GNN flags end at seq 255
    scan_layer<<<256, blk, 0, stream>>>(
        H0, H1, adj, smask, preQc, preQp,
        gruC_Whh, gruP_Wih, gruC_bhh, gruP_bih, attn_W,
        Wr0, Wr1, Mbuf, hxch, Vh, bar, 1,
        lstm_gi, lstm_Whh, lstm_bhh, lstm_hb, lstm_out, 0u);

    // layer-1 preQ
    gemm_nt<<<dim3(64, 24), blk, 0, stream>>>(H1, gruC_Wih + (size_t)1536 * 512,
                                              gruC_bih + 1536, preQc, 4096, 1536, 512, 0);
    gemm_nt<<<dim3(64, 24), blk, 0, stream>>>(H1, gruP_Whh + (size_t)1536 * 512,
                                              gruP_bhh + 1536, preQp, 4096, 1536, 512, 0);

    // layer 1 scan (GNN only, 128 WGs); seq continues from layer 0's 255
    scan_layer<<<128, blk, 0, stream>>>(
        H1, H2, adj, smask, preQc, preQp,
        gruC_Whh + (size_t)1536 * 512, gruP_Wih + (size_t)1536 * 512,
        gruC_bhh + 1536, gruP_bih + 1536, attn_W + 1024,
        Wr0 + (size_t)512 * 512, Wr1 + (size_t)512 * 512,
        Mbuf, hxch, Vh, bar, 0,
        lstm_gi, lstm_Whh, lstm_bhh, lstm_hb, lstm_out, 255u);

    // head
    gemm_cat<<<dim3(64, 8), blk, 0, stream>>>(H0, H1, H2, feat, lstm_out, mlp0_W, mlp0_b, x1);
    gemm_nt<<<dim3(64, 8), blk, 0, stream>>>(x1, mlp1_W, mlp1_b, x2, 4096, 512, 512, 1);
    out_gemm<<<256, blk, 0, stream>>>(x2, out_W, out_b, (float*)d_out);
}

// Round 5
// 6604.631 us; speedup vs baseline: 1.2978x; 1.2652x over previous
//
#include <hip/hip_runtime.h>
#include <math.h>

// Sizes: B=32, N=128, EMB=1024, HID=512, L=2, NCLS=7, IN_DIM=3072, TOK=4096
// Scan: weight-stationary MFMA. 2 GNN pods x 64 WGs x 16 batches. Each WG
// owns 8 h-cols; waves 0-2 hold gate-weight tiles (6 gates x 8 cols) and
// wave 3 holds the V tile ({Wr0|Wr1} 8+8 cols) as bf16 hi/lo B-fragments in
// VGPRs (loaded once). Per step: stage M (bf16) -> 32 MFMAs -> gates/h local
// -> exchange h -> stage h -> V MFMA + hk + softmax + M'. V history in LDS.
// THIS ROUND: all exchange-staging loops are register-batched (issue all
// loads, then LDS-write) so the 16 agent-scope L3 loads pipeline into ~1 RTT
// instead of 16 serial RTTs; combine inputs (preQ/Hin) and adj rows are
// prefetched at phase start so their latency hides under staging/MFMA.
// Cross-WG sync: store-flag barrier. LSTM on WGs 128..255 (layer-0 launch).

typedef __attribute__((ext_vector_type(4))) float f32x4;
typedef __attribute__((ext_vector_type(8))) short s16x8;

#define AGENT __HIP_MEMORY_SCOPE_AGENT

__device__ __forceinline__ float ldc(const float* p) {
    return __hip_atomic_load(p, __ATOMIC_RELAXED, AGENT);
}
__device__ __forceinline__ void stc(float* p, float v) {
    __hip_atomic_store(p, v, __ATOMIC_RELAXED, AGENT);
}
__device__ __forceinline__ unsigned ldcu(const unsigned* p) {
    return __hip_atomic_load(p, __ATOMIC_RELAXED, AGENT);
}
__device__ __forceinline__ void stcu(unsigned* p, unsigned v) {
    __hip_atomic_store(p, v, __ATOMIC_RELAXED, AGENT);
}

// Store-flag pod barrier. All 64 WGs of a pod call with the same monotonic
// seq. Entry __syncthreads + s_waitcnt(0) drain outstanding stores so the
// flag store publishes them. Wave 0 polls all 64 flags (one coalesced 256B
// agent load per iteration).
__device__ __forceinline__ void podsig(unsigned* flags, int w, unsigned seq) {
    __syncthreads();
    if (threadIdx.x == 0) {
        __builtin_amdgcn_s_waitcnt(0);
        stcu(flags + w, seq);
    }
    if (threadIdx.x < 64) {
        while (ldcu(flags + threadIdx.x) < seq) {
            __builtin_amdgcn_s_sleep(1);
        }
    }
    __asm__ __volatile__("" ::: "memory");
    __syncthreads();
}

__global__ void init_bar(int* bar) { bar[threadIdx.x] = 0; }

__device__ __forceinline__ float sigf(float x) { return 1.f / (1.f + __expf(-x)); }

// fp32 -> bf16 (RNE) and back
__device__ __forceinline__ unsigned short f2bf(float f) {
    unsigned u = __float_as_uint(f);
    return (unsigned short)((u + 0x7fffu + ((u >> 16) & 1u)) >> 16);
}
__device__ __forceinline__ float bf2f(unsigned short h) {
    return __uint_as_float(((unsigned)h) << 16);
}

// ---------------------------------------------------------------------------
// Generic fp32 GEMM: C = act(A[M,K] @ W[N,K]^T + bias). 64x64 tile.
// ---------------------------------------------------------------------------
__global__ __launch_bounds__(256) void gemm_nt(
    const float* __restrict__ A, const float* __restrict__ W,
    const float* __restrict__ bias, float* __restrict__ C,
    int M, int N, int K, int relu)
{
    __shared__ float As[16][68];
    __shared__ float Ws[16][68];
    const int tid = threadIdx.x;
    const int m0 = blockIdx.x * 64;
    const int n0 = blockIdx.y * 64;
    const int lr = tid >> 2;
    const int lk = (tid & 3) << 2;
    const int tm = (tid & 15) << 2;
    const int tn = (tid >> 4) << 2;
    float acc[4][4] = {};
    const float* Aptr = A + (size_t)(m0 + lr) * K + lk;
    const float* Wptr = W + (size_t)(n0 + lr) * K + lk;
    for (int k0 = 0; k0 < K; k0 += 16) {
        __syncthreads();
        const float4 av = *(const float4*)(Aptr + k0);
        const float4 wv = *(const float4*)(Wptr + k0);
        As[lk + 0][lr] = av.x; As[lk + 1][lr] = av.y;
        As[lk + 2][lr] = av.z; As[lk + 3][lr] = av.w;
        Ws[lk + 0][lr] = wv.x; Ws[lk + 1][lr] = wv.y;
        Ws[lk + 2][lr] = wv.z; Ws[lk + 3][lr] = wv.w;
        __syncthreads();
        #pragma unroll
        for (int kk = 0; kk < 16; ++kk) {
            float a[4], b[4];
            #pragma unroll
            for (int u = 0; u < 4; ++u) { a[u] = As[kk][tm + u]; b[u] = Ws[kk][tn + u]; }
            #pragma unroll
            for (int ii = 0; ii < 4; ++ii)
                #pragma unroll
                for (int jj = 0; jj < 4; ++jj)
                    acc[ii][jj] += a[ii] * b[jj];
        }
    }
    #pragma unroll
    for (int ii = 0; ii < 4; ++ii)
        #pragma unroll
        for (int jj = 0; jj < 4; ++jj) {
            float v = acc[ii][jj] + bias[n0 + tn + jj];
            if (relu) v = fmaxf(v, 0.f);
            C[(size_t)(m0 + tm + ii) * N + n0 + tn + jj] = v;
        }
}

// ---------------------------------------------------------------------------
// mlp0 with fused 5-way concat
// ---------------------------------------------------------------------------
__global__ __launch_bounds__(256) void gemm_cat(
    const float* __restrict__ H0, const float* __restrict__ H1,
    const float* __restrict__ H2, const float* __restrict__ feat,
    const float* __restrict__ lstm, const float* __restrict__ W,
    const float* __restrict__ bias, float* __restrict__ C)
{
    __shared__ float As[16][68];
    __shared__ float Ws[16][68];
    const int tid = threadIdx.x;
    const int m0 = blockIdx.x * 64;
    const int n0 = blockIdx.y * 64;
    const int lr = tid >> 2;
    const int lk = (tid & 3) << 2;
    const int tm = (tid & 15) << 2;
    const int tn = (tid >> 4) << 2;
    float acc[4][4] = {};
    for (int k0 = 0; k0 < 3072; k0 += 16) {
        const float* src; int kloc, Kp;
        if (k0 < 512)       { src = H0;   kloc = k0;        Kp = 512;  }
        else if (k0 < 1024) { src = H1;   kloc = k0 - 512;  Kp = 512;  }
        else if (k0 < 1536) { src = H2;   kloc = k0 - 1024; Kp = 512;  }
        else if (k0 < 2560) { src = feat; kloc = k0 - 1536; Kp = 1024; }
        else                { src = lstm; kloc = k0 - 2560; Kp = 512;  }
        __syncthreads();
        const float4 av = *(const float4*)(src + (size_t)(m0 + lr) * Kp + kloc + lk);
        const float4 wv = *(const float4*)(W + (size_t)(n0 + lr) * 3072 + k0 + lk);
        As[lk + 0][lr] = av.x; As[lk + 1][lr] = av.y;
        As[lk + 2][lr] = av.z; As[lk + 3][lr] = av.w;
        Ws[lk + 0][lr] = wv.x; Ws[lk + 1][lr] = wv.y;
        Ws[lk + 2][lr] = wv.z; Ws[lk + 3][lr] = wv.w;
        __syncthreads();
        #pragma unroll
        for (int kk = 0; kk < 16; ++kk) {
            float a[4], b[4];
            #pragma unroll
            for (int u = 0; u < 4; ++u) { a[u] = As[kk][tm + u]; b[u] = Ws[kk][tn + u]; }
            #pragma unroll
            for (int ii = 0; ii < 4; ++ii)
                #pragma unroll
                for (int jj = 0; jj < 4; ++jj)
                    acc[ii][jj] += a[ii] * b[jj];
        }
    }
    #pragma unroll
    for (int ii = 0; ii < 4; ++ii)
        #pragma unroll
        for (int jj = 0; jj < 4; ++jj) {
            float v = fmaxf(acc[ii][jj] + bias[n0 + tn + jj], 0.f);
            C[(size_t)(m0 + tm + ii) * 512 + n0 + tn + jj] = v;
        }
}

// ---------------------------------------------------------------------------
// One GNN layer scan (weight-stationary MFMA). Grid 256 (layer 0) / 128.
// LDS map (GNN):            bytes       LDS map (LSTM overlay):
//   MbU   16x520 bf16      0..16640       Msf 16x520 f32  0..33280
//   wkL   512 f32      16640..18688       lgg 512 f32 33280..35328
//   eh    16x132 f32   18688..27136
//   wsf   16x132 f32   27136..35584
//   gg    16x50  f32   35584..38784
//   invZ  16 f32       38784..38848
//   smkr  16x132 f32   38848..47296
//   VhL   16x2056 bf16 47296..112880   (slab = 128*16 + 8 pad elems)
// ---------------------------------------------------------------------------
__global__ __launch_bounds__(256, 1) void scan_layer(
    const float* __restrict__ Hin, float* __restrict__ Hout,
    const float* __restrict__ adj, const float* __restrict__ smk,
    const float* __restrict__ preQc, const float* __restrict__ preQp,
    const float* __restrict__ cWhh, const float* __restrict__ pWih,
    const float* __restrict__ cbhh, const float* __restrict__ pbih,
    const float* __restrict__ attnW,
    const float* __restrict__ Wr0, const float* __restrict__ Wr1,
    unsigned* __restrict__ Mbuf, unsigned* __restrict__ hxch,
    float* __restrict__ Vh, int* __restrict__ bar, const int with_lstm,
    const float* __restrict__ gi, const float* __restrict__ lstm_Whh,
    const float* __restrict__ lstm_bhh, float* __restrict__ lstm_hbuf,
    float* __restrict__ lstm_out, const unsigned seq0)
{
    __shared__ __align__(16) unsigned char smemc[112880];
    unsigned short* MbU = (unsigned short*)smemc;           // 16x520 bf16
    float* wkL  = (float*)(smemc + 16640);                  // 512
    float* eh   = (float*)(smemc + 18688);                  // 16x132
    float* wsf  = (float*)(smemc + 27136);                  // 16x132
    float* gg   = (float*)(smemc + 35584);                  // 16x50
    float* invZ = (float*)(smemc + 38784);                  // 16
    float* smkr = (float*)(smemc + 38848);                  // 16x132
    unsigned short* VhL = (unsigned short*)(smemc + 47296); // 16x(128*16+8)
    (void)Vh;

    const int wg = blockIdx.x, tid = threadIdx.x;

    if (wg >= 128) {
        // =========================== LSTM ================================
        if (!with_lstm) return;
        float* Msf = (float*)smemc;                      // 16x520 fp32
        float* lgg = (float*)(smemc + 33280);            // 512 fp32
        const int lw = wg - 128;
        const int lp = lw >> 6;
        const int wc = lw & 63;
        unsigned* lf = (unsigned*)bar + (2 + lp) * 64;
        const int row0 = lp * 64;
        const int u = tid & 15, rr = tid >> 4;
        const int jc = u & 7, gp = u >> 3;
        const int ghid = wc * 8 + jc;
        const float* wA = lstm_Whh + (size_t)((2 * gp) * 512 + ghid) * 512;
        const float* wB = lstm_Whh + (size_t)((2 * gp + 1) * 512 + ghid) * 512;
        const float bA = lstm_bhh[(2 * gp) * 512 + ghid];
        const float bB = lstm_bhh[(2 * gp + 1) * 512 + ghid];
        float c4[4] = {0.f, 0.f, 0.f, 0.f};
        for (int t = 0; t < 32; ++t) {
            const int par = t & 1;
            for (int rc = 0; rc < 4; ++rc) {
                const int grow = row0 + rc * 16 + rr;
                const float* gir = gi + ((size_t)t * 128 + grow) * 2048;
                // issue gi loads early (independent of staging)
                float sA = bA + gir[(2 * gp) * 512 + ghid];
                float sB = bB + gir[(2 * gp + 1) * 512 + ghid];
                if (t > 0) {
                    const float* hsrc = lstm_hbuf + (size_t)par * 65536
                                      + (size_t)(row0 + rc * 16) * 512;
                    // register-batched staging: 2 chunks of 16 pipelined loads
                    #pragma unroll
                    for (int c = 0; c < 2; ++c) {
                        float r16[16];
                        #pragma unroll
                        for (int k = 0; k < 16; ++k) {
                            const int s = tid + (c * 16 + k) * 256;
                            r16[k] = ldc(hsrc + (size_t)(s >> 9) * 512 + (s & 511));
                        }
                        #pragma unroll
                        for (int k = 0; k < 16; ++k) {
                            const int s = tid + (c * 16 + k) * 256;
                            Msf[(s >> 9) * 520 + (s & 511)] = r16[k];
                        }
                    }
                }
                __syncthreads();
                if (t > 0) {
                    const float* hr = Msf + rr * 520;
                    for (int k = 0; k < 512; k += 4) {
                        const float4 h4 = *(const float4*)(hr + k);
                        const float4 a4 = *(const float4*)(wA + k);
                        const float4 b4 = *(const float4*)(wB + k);
                        sA += h4.x*a4.x + h4.y*a4.y + h4.z*a4.z + h4.w*a4.w;
                        sB += h4.x*b4.x + h4.y*b4.y + h4.z*b4.z + h4.w*b4.w;
                    }
                }
                lgg[rr * 32 + jc * 4 + 2 * gp]     = sA;
                lgg[rr * 32 + jc * 4 + 2 * gp + 1] = sB;
                __syncthreads();
                if (tid < 128) {
                    const int r2 = tid >> 3, j2 = tid & 7;
                    const int grw = row0 + rc * 16 + r2;
                    const int gh2 = wc * 8 + j2;
                    const float si = lgg[r2 * 32 + j2 * 4 + 0];
                    const float sf = lgg[r2 * 32 + j2 * 4 + 1];
                    const float sg = lgg[r2 * 32 + j2 * 4 + 2];
                    const float so = lgg[r2 * 32 + j2 * 4 + 3];
                    const float c = sigf(sf) * c4[rc] + sigf(si) * tanhf(sg);
                    c4[rc] = c;
                    const float h = sigf(so) * tanhf(c);
                    stc(lstm_hbuf + (size_t)(1 - par) * 65536 + (size_t)grw * 512 + gh2, h);
                    lstm_out[((size_t)t * 128 + grw) * 512 + gh2] = h;
                }
                __syncthreads();
            }
            podsig(lf, wc, (unsigned)(t + 1));
        }
        return;
    }

    // ============================= GNN ==================================
    const int pod = wg >> 6, w = wg & 63;
    unsigned* pf = (unsigned*)bar + pod * 64;
    const int b0 = pod * 16, j0 = w * 8;
    const int wv = tid >> 6, lane = tid & 63;
    const int nI = lane & 15, quad = lane >> 4;
    unsigned* MbP = Mbuf + pod * 4096;   // [16][256] bf16-pair dwords
    unsigned* hxP = hxch + pod * 4096;

    for (int s = tid; s < 512; s += 256) wkL[s] = attnW[512 + s];

    // ---- B fragments (hi/lo bf16 split), loaded ONCE into VGPRs ----
    const float* wrow;
    if (wv < 3) {
        const int c = (2 * wv + (nI >> 3)) * 512 + j0 + (nI & 7);
        wrow = (c < 1536) ? cWhh + (size_t)c * 512 : pWih + (size_t)(c - 1536) * 512;
    } else {
        wrow = ((nI >> 3) ? Wr1 : Wr0) + (size_t)(j0 + (nI & 7)) * 512;
    }
    s16x8 Bhi[16], Blo[16];
    #pragma unroll
    for (int kk = 0; kk < 16; ++kk) {
        const float* wp = wrow + kk * 32 + quad * 8;
        s16x8 hi, lo;
        #pragma unroll
        for (int e = 0; e < 8; ++e) {
            const float x = wp[e];
            const unsigned short hb = f2bf(x);
            hi[e] = (short)hb;
            lo[e] = (short)f2bf(x - bf2f(hb));
        }
        Bhi[kk] = hi; Blo[kk] = lo;
    }
    // combine-thread constants (6 gate biases for (b=tid>>3, jc=tid&7))
    const int cb_b = tid >> 3, cb_j = tid & 7;
    float gbias[6];
    if (tid < 128) {
        #pragma unroll
        for (int g = 0; g < 6; ++g) {
            const int c = g * 512 + j0 + cb_j;
            gbias[g] = (c < 1536) ? cbhh[c] : pbih[c - 1536];
        }
    }
    // zero M(0)
    if (w * 256 + tid < 4096) stcu(MbP + w * 256 + tid, 0u);
    podsig(pf, w, seq0 + 1);

    for (int i = 0; i < 128; ++i) {
        // ---------------- Phase 1: stage M, gate MFMA, combine h ---------
        // Prefetch combine inputs (independent of the M exchange) so their
        // latency hides under staging + MFMA.
        float pf_pc0 = 0.f, pf_pc1 = 0.f, pf_pc2 = 0.f;
        float pf_pp0 = 0.f, pf_pp1 = 0.f, pf_pp2 = 0.f, pf_qv = 0.f;
        if (tid < 128) {
            const int bg = b0 + cb_b, j = j0 + cb_j;
            const float* pc = preQc + ((size_t)bg * 128 + i) * 1536;
            const float* pp = preQp + ((size_t)bg * 128 + i) * 1536;
            pf_pc0 = pc[j]; pf_pc1 = pc[512 + j]; pf_pc2 = pc[1024 + j];
            pf_pp0 = pp[j]; pf_pp1 = pp[512 + j]; pf_pp2 = pp[1024 + j];
            pf_qv = Hin[((size_t)bg * 128 + i) * 512 + j];
        }
        // register-batched M staging: issue all 16 loads, then LDS-write
        {
            unsigned mreg[16];
            #pragma unroll
            for (int k = 0; k < 16; ++k) mreg[k] = ldcu(MbP + tid + k * 256);
            #pragma unroll
            for (int k = 0; k < 16; ++k) {
                const int s = tid + k * 256;
                *(unsigned*)(MbU + (s >> 8) * 520 + ((s & 255) << 1)) = mreg[k];
            }
        }
        __syncthreads();
        if (wv < 3) {
            f32x4 acc = {0.f, 0.f, 0.f, 0.f};
            const unsigned short* ab = MbU + nI * 520 + quad * 8;
            #pragma unroll
            for (int kk = 0; kk < 16; ++kk) {
                const s16x8 a = *(const s16x8*)(ab + kk * 32);
                acc = __builtin_amdgcn_mfma_f32_16x16x32_bf16(a, Bhi[kk], acc, 0, 0, 0);
                acc = __builtin_amdgcn_mfma_f32_16x16x32_bf16(a, Blo[kk], acc, 0, 0, 0);
            }
            #pragma unroll
            for (int r = 0; r < 4; ++r)
                gg[(quad * 4 + r) * 50 + wv * 16 + nI] = acc[r];
        }
        __syncthreads();
        if (tid < 128) {
            const int b = cb_b, jc = cb_j, j = j0 + jc, bg = b0 + b;
            const float g0v = gg[b * 50 +  0 + jc] + gbias[0];
            const float g1v = gg[b * 50 +  8 + jc] + gbias[1];
            const float g2v = gg[b * 50 + 16 + jc] + gbias[2];
            const float g3v = gg[b * 50 + 24 + jc] + gbias[3];
            const float g4v = gg[b * 50 + 32 + jc] + gbias[4];
            const float g5v = gg[b * 50 + 40 + jc] + gbias[5];
            const float mv = bf2f(MbU[b * 520 + j]);
            const float rc = sigf(pf_pc0 + g0v);
            const float zc = sigf(pf_pc1 + g1v);
            const float nc = tanhf(pf_pc2 + rc * g2v);
            const float oc = (1.f - zc) * nc + zc * mv;
            const float rp = sigf(g3v + pf_pp0);
            const float zp = sigf(g4v + pf_pp1);
            const float np = tanhf(g5v + rp * pf_pp2);
            const float op = (1.f - zp) * np + zp * pf_qv;
            const float h = oc + op;
            Hout[((size_t)bg * 128 + i) * 512 + j] = h;
            if (i < 127) {
                // fused bf16-pair pack via lane shuffle (partner jc^1)
                const float hN = __shfl_xor(h, 1);
                if ((jc & 1) == 0) {
                    const unsigned d = (unsigned)f2bf(h)
                                     | ((unsigned)f2bf(hN) << 16);
                    stcu(hxP + b * 256 + (j0 >> 1) + (jc >> 1), d);
                }
            }
        }
        if (i == 127) break;   // h(127) written to Hout; nothing downstream
        podsig(pf, w, seq0 + 2 * i + 2);

        // ---------------- Phase 2: stage h + smk row, V MFMA, hk, softmax,
        // ---------------- M' (V history in LDS) --------------------------
        // Batched issue of: h exchange (16), adj row (8, regs), smk row (8).
        unsigned hreg[16];
        #pragma unroll
        for (int k = 0; k < 16; ++k) hreg[k] = ldcu(hxP + tid + k * 256);
        float areg[8];
        {
            const int bq = tid >> 4, u = tid & 15;
            const float* arow = adj + ((size_t)(b0 + bq) * 128 + (i + 1)) * 128;
            #pragma unroll
            for (int kk = 0; kk < 8; ++kk) areg[kk] = arow[u + kk * 16];
        }
        float sreg[8];
        {
            const float* sr = smk + ((size_t)b0 * 128 + (i + 1)) * 128;
            #pragma unroll
            for (int k = 0; k < 8; ++k) {
                const int s = tid + k * 256;
                sreg[k] = sr[(size_t)(s >> 7) * 16384 + (s & 127)];
            }
        }
        #pragma unroll
        for (int k = 0; k < 16; ++k) {
            const int s = tid + k * 256;
            *(unsigned*)(MbU + (s >> 8) * 520 + ((s & 255) << 1)) = hreg[k];
        }
        #pragma unroll
        for (int k = 0; k < 8; ++k) {
            const int s = tid + k * 256;
            smkr[(s >> 7) * 132 + (s & 127)] = sreg[k];
        }
        __syncthreads();
        if (wv == 3) {
            f32x4 acc = {0.f, 0.f, 0.f, 0.f};
            const unsigned short* ab = MbU + nI * 520 + quad * 8;
            #pragma unroll
            for (int kk = 0; kk < 16; ++kk) {
                const s16x8 a = *(const s16x8*)(ab + kk * 32);
                acc = __builtin_amdgcn_mfma_f32_16x16x32_bf16(a, Bhi[kk], acc, 0, 0, 0);
                acc = __builtin_amdgcn_mfma_f32_16x16x32_bf16(a, Blo[kk], acc, 0, 0, 0);
            }
            #pragma unroll
            for (int r = 0; r < 4; ++r) {
                const int b = quad * 4 + r;
                VhL[b * 2056 + i * 16 + nI] = f2bf(acc[r]);
            }
        }
        {   // hk partials (lane-contiguous) + width-16 shuffle reduce
            const int bq = tid >> 4, u = tid & 15;
            const unsigned short* hr = MbU + bq * 520;
            float p = 0.f;
            #pragma unroll
            for (int kk = 0; kk < 32; ++kk) {
                const int k = u + kk * 16;
                p += bf2f(hr[k]) * wkL[k];
            }
            #pragma unroll
            for (int off = 8; off > 0; off >>= 1) p += __shfl_xor(p, off, 16);
            if (u == 0) eh[bq * 132 + i] = p;
        }
        __syncthreads();
        {
            const int bq = tid >> 4, u = tid & 15;
            float amx = -3.0e38f;
            #pragma unroll
            for (int kk = 0; kk < 8; ++kk) {
                const int n = u + kk * 16;
                if (n <= i)
                    amx = fmaxf(amx, eh[bq * 132 + n] - (1.f - areg[kk]) * 1e30f);
            }
            #pragma unroll
            for (int off = 8; off > 0; off >>= 1)
                amx = fmaxf(amx, __shfl_xor(amx, off, 16));
            float es = 0.f;
            #pragma unroll
            for (int kk = 0; kk < 8; ++kk) {
                const int n = u + kk * 16;
                if (n <= i) {
                    const float e = __expf(eh[bq * 132 + n] - (1.f - areg[kk]) * 1e30f - amx);
                    wsf[bq * 132 + n] = e;
                    es += e;
                }
            }
            #pragma unroll
            for (int off = 8; off > 0; off >>= 1) es += __shfl_xor(es, off, 16);
            if (u == 0) invZ[bq] = 1.f / es;
        }
        __syncthreads();
        if (tid < 128) {
            const int b = cb_b, jc = cb_j;
            const float* wrow_ = wsf + b * 132;
            const float* srow_ = smkr + b * 132;
            const unsigned short* vb = VhL + b * 2056 + jc;
            float acc2 = 0.f;
            for (int n = 0; n <= i; ++n) {
                const float wgt = wrow_[n];
                const int sel = (srow_[n] != 0.f) ? 0 : 8;
                acc2 += wgt * bf2f(vb[n * 16 + sel]);
            }
            const float mval = acc2 * invZ[b];
            // fused bf16-pair pack via lane shuffle (partner jc^1)
            const float mN = __shfl_xor(mval, 1);
            if ((jc & 1) == 0) {
                const unsigned d = (unsigned)f2bf(mval)
                                 | ((unsigned)f2bf(mN) << 16);
                stcu(MbP + b * 256 + (j0 >> 1) + (jc >> 1), d);
            }
        }
        podsig(pf, w, seq0 + 2 * i + 3);
    }
}

// ---------------------------------------------------------------------------
__global__ __launch_bounds__(256) void out_gemm(
    const float* __restrict__ x2, const float* __restrict__ W,
    const float* __restrict__ bias, float* __restrict__ out)
{
    __shared__ float xs[16 * 516];
    const int tid = threadIdx.x;
    const int r0 = blockIdx.x * 16;
    for (int idx = tid; idx < 16 * 512; idx += 256) {
        const int rr = idx >> 9, kk = idx & 511;
        xs[rr * 516 + kk] = x2[(size_t)(r0 + rr) * 512 + kk];
    }
    __syncthreads();
    if (tid < 128) {
        const int r = tid >> 3, c = tid & 7;
        if (c < 7) {
            float acc = bias[c];
            const float* wr = W + c * 512;
            const float* xr = xs + r * 516;
            for (int k = 0; k < 512; ++k) acc += xr[k] * wr[k];
            out[(size_t)(r0 + r) * 7 + c] = acc;
        }
    }
}

// ---------------------------------------------------------------------------
extern "C" void kernel_launch(void* const* d_in, const int* in_sizes, int n_in,
                              void* d_out, int out_size, void* d_ws, size_t ws_size,
                              hipStream_t stream) {
    (void)in_sizes; (void)n_in; (void)out_size; (void)ws_size;
    const float* feat     = (const float*)d_in[0];
    const float* adj      = (const float*)d_in[1];
    const float* smask    = (const float*)d_in[2];
    const float* lstm_Wih = (const float*)d_in[5];
    const float* lstm_Whh = (const float*)d_in[6];
    const float* lstm_bih = (const float*)d_in[7];
    const float* lstm_bhh = (const float*)d_in[8];
    const float* fc1_W    = (const float*)d_in[9];
    const float* fc1_b    = (const float*)d_in[10];
    const float* attn_W   = (const float*)d_in[11];
    const float* Wr0      = (const float*)d_in[13];
    const float* Wr1      = (const float*)d_in[14];
    const float* gruC_Wih = (const float*)d_in[15];
    const float* gruC_Whh = (const float*)d_in[16];
    const float* gruC_bih = (const float*)d_in[17];
    const float* gruC_bhh = (const float*)d_in[18];
    const float* gruP_Wih = (const float*)d_in[19];
    const float* gruP_Whh = (const float*)d_in[20];
    const float* gruP_bih = (const float*)d_in[21];
    const float* gruP_bhh = (const float*)d_in[22];
    const float* mlp0_W   = (const float*)d_in[23];
    const float* mlp0_b   = (const float*)d_in[24];
    const float* mlp1_W   = (const float*)d_in[25];
    const float* mlp1_b   = (const float*)d_in[26];
    const float* out_W    = (const float*)d_in[27];
    const float* out_b    = (const float*)d_in[28];

    float* ws       = (float*)d_ws;
    float* lstm_gi  = ws;                        // 8,388,608
    float* lstm_out = lstm_gi + 8388608;         // 2,097,152
    float* H0       = lstm_out + 2097152;        // 2,097,152
    float* H1       = H0 + 2097152;              // 2,097,152
    float* H2       = H1 + 2097152;              // 2,097,152
    float* preQc    = H2 + 2097152;              // 6,291,456
    float* preQp    = preQc + 6291456;           // 6,291,456
    float* x1       = preQp + 6291456;           // 2,097,152
    float* x2       = x1 + 2097152;              // 2,097,152
    unsigned* Mbuf  = (unsigned*)(x2 + 2097152); // 8,192 dwords
    unsigned* hxch  = Mbuf + 8192;               // 8,192 dwords
    float* Vh       = (float*)(hxch + 8192);     // 4,194,304 (unused)
    float* lstm_hb  = Vh + 4194304;              // 131,072
    int*   bar      = (int*)(lstm_hb + 131072);  // 1,024 ints

    const dim3 blk(256);
    init_bar<<<1, 1024, 0, stream>>>(bar);

    // parallel-phase GEMMs
    gemm_nt<<<dim3(64, 8), blk, 0, stream>>>(feat, fc1_W, fc1_b, H0, 4096, 512, 1024, 1);
    gemm_nt<<<dim3(64, 32), blk, 0, stream>>>(feat, lstm_Wih, lstm_bih, lstm_gi, 4096, 2048, 1024, 0);
    gemm_nt<<<dim3(64, 24), blk, 0, stream>>>(H0, gruC_Wih, gruC_bih, preQc, 4096, 1536, 512, 0);
    gemm_nt<<<dim3(64, 24), blk, 0, stream>>>(H0, gruP_Whh, gruP_bhh, preQp, 4096, 1536, 512, 0);

    // layer 0 scan (+ LSTM on WGs 128..255); GNN flags end at seq 255
    scan_layer<<<256, blk, 0, stream>>>(
        H0, H1, adj, smask, preQc, preQp,
        gruC_Whh, gruP_Wih, gruC_bhh, gruP_bih, attn_W,
        Wr0, Wr1, Mbuf, hxch, Vh, bar, 1,
        lstm_gi, lstm_Whh, lstm_bhh, lstm_hb, lstm_out, 0u);

    // layer-1 preQ
    gemm_nt<<<dim3(64, 24), blk, 0, stream>>>(H1, gruC_Wih + (size_t)1536 * 512,
                                              gruC_bih + 1536, preQc, 4096, 1536, 512, 0);
    gemm_nt<<<dim3(64, 24), blk, 0, stream>>>(H1, gruP_Whh + (size_t)1536 * 512,
                                              gruP_bhh + 1536, preQp, 4096, 1536, 512, 0);

    // layer 1 scan (GNN only, 128 WGs); seq continues from layer 0's 255
    scan_layer<<<128, blk, 0, stream>>>(
        H1, H2, adj, smask, preQc, preQp,
        gruC_Whh + (size_t)1536 * 512, gruP_Wih + (size_t)1536 * 512,
        gruC_bhh + 1536, gruP_bih + 1536, attn_W + 1024,
        Wr0 + (size_t)512 * 512, Wr1 + (size_t)512 * 512,
        Mbuf, hxch, Vh, bar, 0,
        lstm_gi, lstm_Whh, lstm_bhh, lstm_hb, lstm_out, 255u);

    // head
    gemm_cat<<<dim3(64, 8), blk, 0, stream>>>(H0, H1, H2, feat, lstm_out, mlp0_W, mlp0_b, x1);
    gemm_nt<<<dim3(64, 8), blk, 0, stream>>>(x1, mlp1_W, mlp1_b, x2, 4096, 512, 512, 1);
    out_gemm<<<256, blk, 0, stream>>>(x2, out_W, out_b, (float*)d_out);
}

// Round 7
// 6568.287 us; speedup vs baseline: 1.3050x; 1.0055x over previous
//
#include <hip/hip_runtime.h>
#include <math.h>

// Sizes: B=32, N=128, EMB=1024, HID=512, L=2, NCLS=7, IN_DIM=3072, TOK=4096
// Scan: weight-stationary MFMA. 2 GNN pods x 64 WGs x 16 batches. Each WG
// owns 8 h-cols; waves 0-2 hold gate-weight tiles and wave 3 the V tile as
// bf16 hi/lo B-fragments in VGPRs. V history in LDS. THIS ROUND:
//  (1) prefetches issued a FULL PHASE ahead (combine inputs during previous
//      phase 2; adj/smk rows at phase-1 top) so __syncthreads vmcnt drains
//      are no-ops instead of ~1us serializers;
//  (2) intra-phase barriers are raw s_barrier + lgkmcnt(0) only (ldsbar) --
//      LDS handoff needs no vmcnt(0), so in-flight global loads survive.
// Cross-WG sync: store-flag barrier. LSTM on WGs 128..255 (layer-0 launch).

typedef __attribute__((ext_vector_type(4))) float f32x4;
typedef __attribute__((ext_vector_type(8))) short s16x8;

#define AGENT __HIP_MEMORY_SCOPE_AGENT

__device__ __forceinline__ float ldc(const float* p) {
    return __hip_atomic_load(p, __ATOMIC_RELAXED, AGENT);
}
__device__ __forceinline__ void stc(float* p, float v) {
    __hip_atomic_store(p, v, __ATOMIC_RELAXED, AGENT);
}
__device__ __forceinline__ unsigned ldcu(const unsigned* p) {
    return __hip_atomic_load(p, __ATOMIC_RELAXED, AGENT);
}
__device__ __forceinline__ void stcu(unsigned* p, unsigned v) {
    __hip_atomic_store(p, v, __ATOMIC_RELAXED, AGENT);
}

// LDS-only barrier: waits DS ops, does NOT drain vmcnt (in-flight global
// loads survive). asm memory clobbers pin IR ordering around the barrier.
__device__ __forceinline__ void ldsbar() {
    __asm__ __volatile__("s_waitcnt lgkmcnt(0)" ::: "memory");
    __builtin_amdgcn_s_barrier();
    __asm__ __volatile__("" ::: "memory");
}

// Store-flag pod barrier. Entry __syncthreads drains each wave's stores so
// the flag store publishes them. Wave 0 polls all 64 flags (one coalesced
// 256B agent load per iteration).
__device__ __forceinline__ void podsig(unsigned* flags, int w, unsigned seq) {
    __syncthreads();
    if (threadIdx.x == 0) {
        __builtin_amdgcn_s_waitcnt(0);
        stcu(flags + w, seq);
    }
    if (threadIdx.x < 64) {
        while (ldcu(flags + threadIdx.x) < seq) {
            __builtin_amdgcn_s_sleep(1);
        }
    }
    __asm__ __volatile__("" ::: "memory");
    __syncthreads();
}

__global__ void init_bar(int* bar) { bar[threadIdx.x] = 0; }

__device__ __forceinline__ float sigf(float x) { return 1.f / (1.f + __expf(-x)); }

// fp32 -> bf16 (RNE) and back
__device__ __forceinline__ unsigned short f2bf(float f) {
    unsigned u = __float_as_uint(f);
    return (unsigned short)((u + 0x7fffu + ((u >> 16) & 1u)) >> 16);
}
__device__ __forceinline__ float bf2f(unsigned short h) {
    return __uint_as_float(((unsigned)h) << 16);
}

// ---------------------------------------------------------------------------
// Generic fp32 GEMM: C = act(A[M,K] @ W[N,K]^T + bias). 64x64 tile.
// ---------------------------------------------------------------------------
__global__ __launch_bounds__(256) void gemm_nt(
    const float* __restrict__ A, const float* __restrict__ W,
    const float* __restrict__ bias, float* __restrict__ C,
    int M, int N, int K, int relu)
{
    __shared__ float As[16][68];
    __shared__ float Ws[16][68];
    const int tid = threadIdx.x;
    const int m0 = blockIdx.x * 64;
    const int n0 = blockIdx.y * 64;
    const int lr = tid >> 2;
    const int lk = (tid & 3) << 2;
    const int tm = (tid & 15) << 2;
    const int tn = (tid >> 4) << 2;
    float acc[4][4] = {};
    const float* Aptr = A + (size_t)(m0 + lr) * K + lk;
    const float* Wptr = W + (size_t)(n0 + lr) * K + lk;
    for (int k0 = 0; k0 < K; k0 += 16) {
        __syncthreads();
        const float4 av = *(const float4*)(Aptr + k0);
        const float4 wv = *(const float4*)(Wptr + k0);
        As[lk + 0][lr] = av.x; As[lk + 1][lr] = av.y;
        As[lk + 2][lr] = av.z; As[lk + 3][lr] = av.w;
        Ws[lk + 0][lr] = wv.x; Ws[lk + 1][lr] = wv.y;
        Ws[lk + 2][lr] = wv.z; Ws[lk + 3][lr] = wv.w;
        __syncthreads();
        #pragma unroll
        for (int kk = 0; kk < 16; ++kk) {
            float a[4], b[4];
            #pragma unroll
            for (int u = 0; u < 4; ++u) { a[u] = As[kk][tm + u]; b[u] = Ws[kk][tn + u]; }
            #pragma unroll
            for (int ii = 0; ii < 4; ++ii)
                #pragma unroll
                for (int jj = 0; jj < 4; ++jj)
                    acc[ii][jj] += a[ii] * b[jj];
        }
    }
    #pragma unroll
    for (int ii = 0; ii < 4; ++ii)
        #pragma unroll
        for (int jj = 0; jj < 4; ++jj) {
            float v = acc[ii][jj] + bias[n0 + tn + jj];
            if (relu) v = fmaxf(v, 0.f);
            C[(size_t)(m0 + tm + ii) * N + n0 + tn + jj] = v;
        }
}

// ---------------------------------------------------------------------------
// mlp0 with fused 5-way concat
// ---------------------------------------------------------------------------
__global__ __launch_bounds__(256) void gemm_cat(
    const float* __restrict__ H0, const float* __restrict__ H1,
    const float* __restrict__ H2, const float* __restrict__ feat,
    const float* __restrict__ lstm, const float* __restrict__ W,
    const float* __restrict__ bias, float* __restrict__ C)
{
    __shared__ float As[16][68];
    __shared__ float Ws[16][68];
    const int tid = threadIdx.x;
    const int m0 = blockIdx.x * 64;
    const int n0 = blockIdx.y * 64;
    const int lr = tid >> 2;
    const int lk = (tid & 3) << 2;
    const int tm = (tid & 15) << 2;
    const int tn = (tid >> 4) << 2;
    float acc[4][4] = {};
    for (int k0 = 0; k0 < 3072; k0 += 16) {
        const float* src; int kloc, Kp;
        if (k0 < 512)       { src = H0;   kloc = k0;        Kp = 512;  }
        else if (k0 < 1024) { src = H1;   kloc = k0 - 512;  Kp = 512;  }
        else if (k0 < 1536) { src = H2;   kloc = k0 - 1024; Kp = 512;  }
        else if (k0 < 2560) { src = feat; kloc = k0 - 1536; Kp = 1024; }
        else                { src = lstm; kloc = k0 - 2560; Kp = 512;  }
        __syncthreads();
        const float4 av = *(const float4*)(src + (size_t)(m0 + lr) * Kp + kloc + lk);
        const float4 wv = *(const float4*)(W + (size_t)(n0 + lr) * 3072 + k0 + lk);
        As[lk + 0][lr] = av.x; As[lk + 1][lr] = av.y;
        As[lk + 2][lr] = av.z; As[lk + 3][lr] = av.w;
        Ws[lk + 0][lr] = wv.x; Ws[lk + 1][lr] = wv.y;
        Ws[lk + 2][lr] = wv.z; Ws[lk + 3][lr] = wv.w;
        __syncthreads();
        #pragma unroll
        for (int kk = 0; kk < 16; ++kk) {
            float a[4], b[4];
            #pragma unroll
            for (int u = 0; u < 4; ++u) { a[u] = As[kk][tm + u]; b[u] = Ws[kk][tn + u]; }
            #pragma unroll
            for (int ii = 0; ii < 4; ++ii)
                #pragma unroll
                for (int jj = 0; jj < 4; ++jj)
                    acc[ii][jj] += a[ii] * b[jj];
        }
    }
    #pragma unroll
    for (int ii = 0; ii < 4; ++ii)
        #pragma unroll
        for (int jj = 0; jj < 4; ++jj) {
            float v = fmaxf(acc[ii][jj] + bias[n0 + tn + jj], 0.f);
            C[(size_t)(m0 + tm + ii) * 512 + n0 + tn + jj] = v;
        }
}

// ---------------------------------------------------------------------------
// One GNN layer scan (weight-stationary MFMA). Grid 256 (layer 0) / 128.
// LDS map (GNN):            bytes       LDS map (LSTM overlay):
//   MbU   16x520 bf16      0..16640       Msf 16x520 f32  0..33280
//   wkL   512 f32      16640..18688       lgg 512 f32 33280..35328
//   eh    16x132 f32   18688..27136
//   wsf   16x132 f32   27136..35584
//   gg    16x50  f32   35584..38784
//   invZ  16 f32       38784..38848
//   smkr  16x132 f32   38848..47296
//   VhL   16x2056 bf16 47296..112880   (slab = 128*16 + 8 pad elems)
// ---------------------------------------------------------------------------
__global__ __launch_bounds__(256, 1) void scan_layer(
    const float* __restrict__ Hin, float* __restrict__ Hout,
    const float* __restrict__ adj, const float* __restrict__ smk,
    const float* __restrict__ preQc, const float* __restrict__ preQp,
    const float* __restrict__ cWhh, const float* __restrict__ pWih,
    const float* __restrict__ cbhh, const float* __restrict__ pbih,
    const float* __restrict__ attnW,
    const float* __restrict__ Wr0, const float* __restrict__ Wr1,
    unsigned* __restrict__ Mbuf, unsigned* __restrict__ hxch,
    float* __restrict__ Vh, int* __restrict__ bar, const int with_lstm,
    const float* __restrict__ gi, const float* __restrict__ lstm_Whh,
    const float* __restrict__ lstm_bhh, float* __restrict__ lstm_hbuf,
    float* __restrict__ lstm_out, const unsigned seq0)
{
    __shared__ __align__(16) unsigned char smemc[112880];
    unsigned short* MbU = (unsigned short*)smemc;           // 16x520 bf16
    float* wkL  = (float*)(smemc + 16640);                  // 512
    float* eh   = (float*)(smemc + 18688);                  // 16x132
    float* wsf  = (float*)(smemc + 27136);                  // 16x132
    float* gg   = (float*)(smemc + 35584);                  // 16x50
    float* invZ = (float*)(smemc + 38784);                  // 16
    float* smkr = (float*)(smemc + 38848);                  // 16x132
    unsigned short* VhL = (unsigned short*)(smemc + 47296); // 16x(128*16+8)
    (void)Vh;

    const int wg = blockIdx.x, tid = threadIdx.x;

    if (wg >= 128) {
        // =========================== LSTM ================================
        if (!with_lstm) return;
        float* Msf = (float*)smemc;                      // 16x520 fp32
        float* lgg = (float*)(smemc + 33280);            // 512 fp32
        const int lw = wg - 128;
        const int lp = lw >> 6;
        const int wc = lw & 63;
        unsigned* lf = (unsigned*)bar + (2 + lp) * 64;
        const int row0 = lp * 64;
        const int u = tid & 15, rr = tid >> 4;
        const int jc = u & 7, gp = u >> 3;
        const int ghid = wc * 8 + jc;
        const float* wA = lstm_Whh + (size_t)((2 * gp) * 512 + ghid) * 512;
        const float* wB = lstm_Whh + (size_t)((2 * gp + 1) * 512 + ghid) * 512;
        const float bA = lstm_bhh[(2 * gp) * 512 + ghid];
        const float bB = lstm_bhh[(2 * gp + 1) * 512 + ghid];
        float c4[4] = {0.f, 0.f, 0.f, 0.f};
        for (int t = 0; t < 32; ++t) {
            const int par = t & 1;
            for (int rc = 0; rc < 4; ++rc) {
                const int grow = row0 + rc * 16 + rr;
                const float* gir = gi + ((size_t)t * 128 + grow) * 2048;
                // issue gi loads early (independent of staging)
                float sA = bA + gir[(2 * gp) * 512 + ghid];
                float sB = bB + gir[(2 * gp + 1) * 512 + ghid];
                if (t > 0) {
                    const float* hsrc = lstm_hbuf + (size_t)par * 65536
                                      + (size_t)(row0 + rc * 16) * 512;
                    // register-batched staging: 2 chunks of 16 pipelined loads
                    #pragma unroll
                    for (int c = 0; c < 2; ++c) {
                        float r16[16];
                        #pragma unroll
                        for (int k = 0; k < 16; ++k) {
                            const int s = tid + (c * 16 + k) * 256;
                            r16[k] = ldc(hsrc + (size_t)(s >> 9) * 512 + (s & 511));
                        }
                        #pragma unroll
                        for (int k = 0; k < 16; ++k) {
                            const int s = tid + (c * 16 + k) * 256;
                            Msf[(s >> 9) * 520 + (s & 511)] = r16[k];
                        }
                    }
                }
                __syncthreads();
                if (t > 0) {
                    const float* hr = Msf + rr * 520;
                    for (int k = 0; k < 512; k += 4) {
                        const float4 h4 = *(const float4*)(hr + k);
                        const float4 a4 = *(const float4*)(wA + k);
                        const float4 b4 = *(const float4*)(wB + k);
                        sA += h4.x*a4.x + h4.y*a4.y + h4.z*a4.z + h4.w*a4.w;
                        sB += h4.x*b4.x + h4.y*b4.y + h4.z*b4.z + h4.w*b4.w;
                    }
                }
                lgg[rr * 32 + jc * 4 + 2 * gp]     = sA;
                lgg[rr * 32 + jc * 4 + 2 * gp + 1] = sB;
                __syncthreads();
                if (tid < 128) {
                    const int r2 = tid >> 3, j2 = tid & 7;
                    const int grw = row0 + rc * 16 + r2;
                    const int gh2 = wc * 8 + j2;
                    const float si = lgg[r2 * 32 + j2 * 4 + 0];
                    const float sf = lgg[r2 * 32 + j2 * 4 + 1];
                    const float sg = lgg[r2 * 32 + j2 * 4 + 2];
                    const float so = lgg[r2 * 32 + j2 * 4 + 3];
                    const float c = sigf(sf) * c4[rc] + sigf(si) * tanhf(sg);
                    c4[rc] = c;
                    const float h = sigf(so) * tanhf(c);
                    stc(lstm_hbuf + (size_t)(1 - par) * 65536 + (size_t)grw * 512 + gh2, h);
                    lstm_out[((size_t)t * 128 + grw) * 512 + gh2] = h;
                }
                __syncthreads();
            }
            podsig(lf, wc, (unsigned)(t + 1));
        }
        return;
    }

    // ============================= GNN ==================================
    const int pod = wg >> 6, w = wg & 63;
    unsigned* pf = (unsigned*)bar + pod * 64;
    const int b0 = pod * 16, j0 = w * 8;
    const int wv = tid >> 6, lane = tid & 63;
    const int nI = lane & 15, quad = lane >> 4;
    unsigned* MbP = Mbuf + pod * 4096;   // [16][256] bf16-pair dwords
    unsigned* hxP = hxch + pod * 4096;

    for (int s = tid; s < 512; s += 256) wkL[s] = attnW[512 + s];

    // ---- B fragments (hi/lo bf16 split), loaded ONCE into VGPRs ----
    const float* wrow;
    if (wv < 3) {
        const int c = (2 * wv + (nI >> 3)) * 512 + j0 + (nI & 7);
        wrow = (c < 1536) ? cWhh + (size_t)c * 512 : pWih + (size_t)(c - 1536) * 512;
    } else {
        wrow = ((nI >> 3) ? Wr1 : Wr0) + (size_t)(j0 + (nI & 7)) * 512;
    }
    s16x8 Bhi[16], Blo[16];
    #pragma unroll
    for (int kk = 0; kk < 16; ++kk) {
        const float* wp = wrow + kk * 32 + quad * 8;
        s16x8 hi, lo;
        #pragma unroll
        for (int e = 0; e < 8; ++e) {
            const float x = wp[e];
            const unsigned short hb = f2bf(x);
            hi[e] = (short)hb;
            lo[e] = (short)f2bf(x - bf2f(hb));
        }
        Bhi[kk] = hi; Blo[kk] = lo;
    }
    // combine-thread constants (6 gate biases for (b=tid>>3, jc=tid&7))
    const int cb_b = tid >> 3, cb_j = tid & 7;
    float gbias[6];
    if (tid < 128) {
        #pragma unroll
        for (int g = 0; g < 6; ++g) {
            const int c = g * 512 + j0 + cb_j;
            gbias[g] = (c < 1536) ? cbhh[c] : pbih[c - 1536];
        }
    }

    // persistent prefetch registers (combine inputs / attn rows)
    float cf0 = 0.f, cf1 = 0.f, cf2 = 0.f, cf3 = 0.f, cf4 = 0.f, cf5 = 0.f,
          cf6 = 0.f;
    float areg[8], sreg[8];

    // issue combine prefetch for step 0 (completes during init barrier)
    if (tid < 128) {
        const int bg = b0 + cb_b, j = j0 + cb_j;
        const float* pc = preQc + (size_t)bg * 128 * 1536;
        const float* pp = preQp + (size_t)bg * 128 * 1536;
        cf0 = pc[j]; cf1 = pc[512 + j]; cf2 = pc[1024 + j];
        cf3 = pp[j]; cf4 = pp[512 + j]; cf5 = pp[1024 + j];
        cf6 = Hin[(size_t)bg * 128 * 512 + j];
    }
    // zero M(0)
    if (w * 256 + tid < 4096) stcu(MbP + w * 256 + tid, 0u);
    podsig(pf, w, seq0 + 1);

    for (int i = 0; i < 128; ++i) {
        // ---------------- Phase 1: stage M, gate MFMA, combine h ---------
        // Issue NEXT-PHASE (phase-2) attn prefetches now: row i+1 of adj/smk.
        // They complete well before phase 2's first consumer sync.
        if (i < 127) {
            const int bq = tid >> 4, u = tid & 15;
            const float* arow = adj + ((size_t)(b0 + bq) * 128 + (i + 1)) * 128;
            #pragma unroll
            for (int kk = 0; kk < 8; ++kk) areg[kk] = arow[u + kk * 16];
            const float* sr = smk + ((size_t)b0 * 128 + (i + 1)) * 128;
            #pragma unroll
            for (int k = 0; k < 8; ++k) {
                const int s = tid + k * 256;
                sreg[k] = sr[(size_t)(s >> 7) * 16384 + (s & 127)];
            }
        }
        // register-batched M staging: issue all 16 loads, then LDS-write
        {
            unsigned mreg[16];
            #pragma unroll
            for (int k = 0; k < 16; ++k) mreg[k] = ldcu(MbP + tid + k * 256);
            #pragma unroll
            for (int k = 0; k < 16; ++k) {
                const int s = tid + k * 256;
                *(unsigned*)(MbU + (s >> 8) * 520 + ((s & 255) << 1)) = mreg[k];
            }
        }
        ldsbar();
        if (wv < 3) {
            f32x4 acc = {0.f, 0.f, 0.f, 0.f};
            const unsigned short* ab = MbU + nI * 520 + quad * 8;
            #pragma unroll
            for (int kk = 0; kk < 16; ++kk) {
                const s16x8 a = *(const s16x8*)(ab + kk * 32);
                acc = __builtin_amdgcn_mfma_f32_16x16x32_bf16(a, Bhi[kk], acc, 0, 0, 0);
                acc = __builtin_amdgcn_mfma_f32_16x16x32_bf16(a, Blo[kk], acc, 0, 0, 0);
            }
            #pragma unroll
            for (int r = 0; r < 4; ++r)
                gg[(quad * 4 + r) * 50 + wv * 16 + nI] = acc[r];
        }
        ldsbar();
        if (tid < 128) {
            const int b = cb_b, jc = cb_j, j = j0 + jc, bg = b0 + b;
            const float g0v = gg[b * 50 +  0 + jc] + gbias[0];
            const float g1v = gg[b * 50 +  8 + jc] + gbias[1];
            const float g2v = gg[b * 50 + 16 + jc] + gbias[2];
            const float g3v = gg[b * 50 + 24 + jc] + gbias[3];
            const float g4v = gg[b * 50 + 32 + jc] + gbias[4];
            const float g5v = gg[b * 50 + 40 + jc] + gbias[5];
            const float mv = bf2f(MbU[b * 520 + j]);
            const float rc = sigf(cf0 + g0v);
            const float zc = sigf(cf1 + g1v);
            const float nc = tanhf(cf2 + rc * g2v);
            const float oc = (1.f - zc) * nc + zc * mv;
            const float rp = sigf(g3v + cf3);
            const float zp = sigf(g4v + cf4);
            const float np = tanhf(g5v + rp * cf5);
            const float op = (1.f - zp) * np + zp * cf6;
            const float h = oc + op;
            Hout[((size_t)bg * 128 + i) * 512 + j] = h;
            if (i < 127) {
                // fused bf16-pair pack via lane shuffle (partner jc^1)
                const float hN = __shfl_xor(h, 1);
                if ((jc & 1) == 0) {
                    const unsigned d = (unsigned)f2bf(h)
                                     | ((unsigned)f2bf(hN) << 16);
                    stcu(hxP + b * 256 + (j0 >> 1) + (jc >> 1), d);
                }
            }
        }
        if (i == 127) break;   // h(127) written to Hout; nothing downstream
        podsig(pf, w, seq0 + 2 * i + 2);

        // ---------------- Phase 2: stage h + smk row, V MFMA, hk, softmax,
        // ---------------- M' (V history in LDS) --------------------------
        // Issue NEXT-STEP combine prefetch now (consumed in phase 1 of i+1).
        if (tid < 128) {
            const int bg = b0 + cb_b, j = j0 + cb_j;
            const float* pc = preQc + ((size_t)bg * 128 + (i + 1)) * 1536;
            const float* pp = preQp + ((size_t)bg * 128 + (i + 1)) * 1536;
            cf0 = pc[j]; cf1 = pc[512 + j]; cf2 = pc[1024 + j];
            cf3 = pp[j]; cf4 = pp[512 + j]; cf5 = pp[1024 + j];
            cf6 = Hin[((size_t)bg * 128 + (i + 1)) * 512 + j];
        }
        // register-batched h staging + smkr write from prefetched sreg
        {
            unsigned hreg[16];
            #pragma unroll
            for (int k = 0; k < 16; ++k) hreg[k] = ldcu(hxP + tid + k * 256);
            #pragma unroll
            for (int k = 0; k < 16; ++k) {
                const int s = tid + k * 256;
                *(unsigned*)(MbU + (s >> 8) * 520 + ((s & 255) << 1)) = hreg[k];
            }
            #pragma unroll
            for (int k = 0; k < 8; ++k) {
                const int s = tid + k * 256;
                smkr[(s >> 7) * 132 + (s & 127)] = sreg[k];
            }
        }
        ldsbar();
        if (wv == 3) {
            f32x4 acc = {0.f, 0.f, 0.f, 0.f};
            const unsigned short* ab = MbU + nI * 520 + quad * 8;
            #pragma unroll
            for (int kk = 0; kk < 16; ++kk) {
                const s16x8 a = *(const s16x8*)(ab + kk * 32);
                acc = __builtin_amdgcn_mfma_f32_16x16x32_bf16(a, Bhi[kk], acc, 0, 0, 0);
                acc = __builtin_amdgcn_mfma_f32_16x16x32_bf16(a, Blo[kk], acc, 0, 0, 0);
            }
            #pragma unroll
            for (int r = 0; r < 4; ++r) {
                const int b = quad * 4 + r;
                VhL[b * 2056 + i * 16 + nI] = f2bf(acc[r]);
            }
        }
        {   // hk partials (lane-contiguous) + width-16 shuffle reduce
            const int bq = tid >> 4, u = tid & 15;
            const unsigned short* hr = MbU + bq * 520;
            float p = 0.f;
            #pragma unroll
            for (int kk = 0; kk < 32; ++kk) {
                const int k = u + kk * 16;
                p += bf2f(hr[k]) * wkL[k];
            }
            #pragma unroll
            for (int off = 8; off > 0; off >>= 1) p += __shfl_xor(p, off, 16);
            if (u == 0) eh[bq * 132 + i] = p;
        }
        ldsbar();
        {
            const int bq = tid >> 4, u = tid & 15;
            float amx = -3.0e38f;
            #pragma unroll
            for (int kk = 0; kk < 8; ++kk) {
                const int n = u + kk * 16;
                if (n <= i)
                    amx = fmaxf(amx, eh[bq * 132 + n] - (1.f - areg[kk]) * 1e30f);
            }
            #pragma unroll
            for (int off = 8; off > 0; off >>= 1)
                amx = fmaxf(amx, __shfl_xor(amx, off, 16));
            float es = 0.f;
            #pragma unroll
            for (int kk = 0; kk < 8; ++kk) {
                const int n = u + kk * 16;
                if (n <= i) {
                    const float e = __expf(eh[bq * 132 + n] - (1.f - areg[kk]) * 1e30f - amx);
                    wsf[bq * 132 + n] = e;
                    es += e;
                }
            }
            #pragma unroll
            for (int off = 8; off > 0; off >>= 1) es += __shfl_xor(es, off, 16);
            if (u == 0) invZ[bq] = 1.f / es;
        }
        ldsbar();
        if (tid < 128) {
            const int b = cb_b, jc = cb_j;
            const float* wrow_ = wsf + b * 132;
            const float* srow_ = smkr + b * 132;
            const unsigned short* vb = VhL + b * 2056 + jc;
            float acc2 = 0.f;
            for (int n = 0; n <= i; ++n) {
                const float wgt = wrow_[n];
                const int sel = (srow_[n] != 0.f) ? 0 : 8;
                acc2 += wgt * bf2f(vb[n * 16 + sel]);
            }
            const float mval = acc2 * invZ[b];
            // fused bf16-pair pack via lane shuffle (partner jc^1)
            const float mN = __shfl_xor(mval, 1);
            if ((jc & 1) == 0) {
                const unsigned d = (unsigned)f2bf(mval)
                                 | ((unsigned)f2bf(mN) << 16);
                stcu(MbP + b * 256 + (j0 >> 1) + (jc >> 1), d);
            }
        }
        podsig(pf, w, seq0 + 2 * i + 3);
    }
}

// ---------------------------------------------------------------------------
__global__ __launch_bounds__(256) void out_gemm(
    const float* __restrict__ x2, const float* __restrict__ W,
    const float* __restrict__ bias, float* __restrict__ out)
{
    __shared__ float xs[16 * 516];
    const int tid = threadIdx.x;
    const int r0 = blockIdx.x * 16;
    for (int idx = tid; idx < 16 * 512; idx += 256) {
        const int rr = idx >> 9, kk = idx & 511;
        xs[rr * 516 + kk] = x2[(size_t)(r0 + rr) * 512 + kk];
    }
    __syncthreads();
    if (tid < 128) {
        const int r = tid >> 3, c = tid & 7;
        if (c < 7) {
            float acc = bias[c];
            const float* wr = W + c * 512;
            const float* xr = xs + r * 516;
            for (int k = 0; k < 512; ++k) acc += xr[k] * wr[k];
            out[(size_t)(r0 + r) * 7 + c] = acc;
        }
    }
}

// ---------------------------------------------------------------------------
extern "C" void kernel_launch(void* const* d_in, const int* in_sizes, int n_in,
                              void* d_out, int out_size, void* d_ws, size_t ws_size,
                              hipStream_t stream) {
    (void)in_sizes; (void)n_in; (void)out_size; (void)ws_size;
    const float* feat     = (const float*)d_in[0];
    const float* adj      = (const float*)d_in[1];
    const float* smask    = (const float*)d_in[2];
    const float* lstm_Wih = (const float*)d_in[5];
    const float* lstm_Whh = (const float*)d_in[6];
    const float* lstm_bih = (const float*)d_in[7];
    const float* lstm_bhh = (const float*)d_in[8];
    const float* fc1_W    = (const float*)d_in[9];
    const float* fc1_b    = (const float*)d_in[10];
    const float* attn_W   = (const float*)d_in[11];
    const float* Wr0      = (const float*)d_in[13];
    const float* Wr1      = (const float*)d_in[14];
    const float* gruC_Wih = (const float*)d_in[15];
    const float* gruC_Whh = (const float*)d_in[16];
    const float* gruC_bih = (const float*)d_in[17];
    const float* gruC_bhh = (const float*)d_in[18];
    const float* gruP_Wih = (const float*)d_in[19];
    const float* gruP_Whh = (const float*)d_in[20];
    const float* gruP_bih = (const float*)d_in[21];
    const float* gruP_bhh = (const float*)d_in[22];
    const float* mlp0_W   = (const float*)d_in[23];
    const float* mlp0_b   = (const float*)d_in[24];
    const float* mlp1_W   = (const float*)d_in[25];
    const float* mlp1_b   = (const float*)d_in[26];
    const float* out_W    = (const float*)d_in[27];
    const float* out_b    = (const float*)d_in[28];

    float* ws       = (float*)d_ws;
    float* lstm_gi  = ws;                        // 8,388,608
    float* lstm_out = lstm_gi + 8388608;         // 2,097,152
    float* H0       = lstm_out + 2097152;        // 2,097,152
    float* H1       = H0 + 2097152;              // 2,097,152
    float* H2       = H1 + 2097152;              // 2,097,152
    float* preQc    = H2 + 2097152;              // 6,291,456
    float* preQp    = preQc + 6291456;           // 6,291,456
    float* x1       = preQp + 6291456;           // 2,097,152
    float* x2       = x1 + 2097152;              // 2,097,152
    unsigned* Mbuf  = (unsigned*)(x2 + 2097152); // 8,192 dwords
    unsigned* hxch  = Mbuf + 8192;               // 8,192 dwords
    float* Vh       = (float*)(hxch + 8192);     // 4,194,304 (unused)
    float* lstm_hb  = Vh + 4194304;              // 131,072
    int*   bar      = (int*)(lstm_hb + 131072);  // 1,024 ints

    const dim3 blk(256);
    init_bar<<<1, 1024, 0, stream>>>(bar);

    // parallel-phase GEMMs
    gemm_nt<<<dim3(64, 8), blk, 0, stream>>>(feat, fc1_W, fc1_b, H0, 4096, 512, 1024, 1);
    gemm_nt<<<dim3(64, 32), blk, 0, stream>>>(feat, lstm_Wih, lstm_bih, lstm_gi, 4096, 2048, 1024, 0);
    gemm_nt<<<dim3(64, 24), blk, 0, stream>>>(H0, gruC_Wih, gruC_bih, preQc, 4096, 1536, 512, 0);
    gemm_nt<<<dim3(64, 24), blk, 0, stream>>>(H0, gruP_Whh, gruP_bhh, preQp, 4096, 1536, 512, 0);

    // layer 0 scan (+ LSTM on WGs 128..255); GNN flags end at seq 255
    scan_layer<<<256, blk, 0, stream>>>(
        H0, H1, adj, smask, preQc, preQp,
        gruC_Whh, gruP_Wih, gruC_bhh, gruP_bih, attn_W,
        Wr0, Wr1, Mbuf, hxch, Vh, bar, 1,
        lstm_gi, lstm_Whh, lstm_bhh, lstm_hb, lstm_out, 0u);

    // layer-1 preQ
    gemm_nt<<<dim3(64, 24), blk, 0, stream>>>(H1, gruC_Wih + (size_t)1536 * 512,
                                              gruC_bih + 1536, preQc, 4096, 1536, 512, 0);
    gemm_nt<<<dim3(64, 24), blk, 0, stream>>>(H1, gruP_Whh + (size_t)1536 * 512,
                                              gruP_bhh + 1536, preQp, 4096, 1536, 512, 0);

    // layer 1 scan (GNN only, 128 WGs); seq continues from layer 0's 255
    scan_layer<<<128, blk, 0, stream>>>(
        H1, H2, adj, smask, preQc, preQp,
        gruC_Whh + (size_t)1536 * 512, gruP_Wih + (size_t)1536 * 512,
        gruC_bhh + 1536, gruP_bih + 1536, attn_W + 1024,
        Wr0 + (size_t)512 * 512, Wr1 + (size_t)512 * 512,
        Mbuf, hxch, Vh, bar, 0,
        lstm_gi, lstm_Whh, lstm_bhh, lstm_hb, lstm_out, 255u);

    // head
    gemm_cat<<<dim3(64, 8), blk, 0, stream>>>(H0, H1, H2, feat, lstm_out, mlp0_W, mlp0_b, x1);
    gemm_nt<<<dim3(64, 8), blk, 0, stream>>>(x1, mlp1_W, mlp1_b, x2, 4096, 512, 512, 1);
    out_gemm<<<256, blk, 0, stream>>>(x2, out_W, out_b, (float*)d_out);
}

// Round 10
// 6499.542 us; speedup vs baseline: 1.3188x; 1.0106x over previous
//
#include <hip/hip_runtime.h>
#include <math.h>

// Sizes: B=32, N=128, EMB=1024, HID=512, L=2, NCLS=7, IN_DIM=3072, TOK=4096
// Scan: weight-stationary MFMA. 2 GNN pods x 64 WGs x 16 batches. Each WG
// owns 8 h-cols; waves 0-2 hold gate-weight tiles and wave 3 the V tile as
// bf16 hi/lo B-fragments in VGPRs. V history in LDS. THIS ROUND:
//  (1) M' weighted sum: both V candidates loaded at static addresses +
//      cndmask select (kills the dependent srow->vb LDS address chain), and
//      n-loop split even/odd across all 256 threads (waves 2-3 now help),
//      combined via shfl_xor width-16;
//  (2) podsig: ALL waves poll the 64 flags (exit __syncthreads removed) so
//      each wave starts its staging loads the moment readiness is visible.
// Cross-WG sync: store-flag barrier. LSTM on WGs 128..255 (layer-0 launch).

typedef __attribute__((ext_vector_type(4))) float f32x4;
typedef __attribute__((ext_vector_type(8))) short s16x8;

#define AGENT __HIP_MEMORY_SCOPE_AGENT

__device__ __forceinline__ float ldc(const float* p) {
    return __hip_atomic_load(p, __ATOMIC_RELAXED, AGENT);
}
__device__ __forceinline__ void stc(float* p, float v) {
    __hip_atomic_store(p, v, __ATOMIC_RELAXED, AGENT);
}
__device__ __forceinline__ unsigned ldcu(const unsigned* p) {
    return __hip_atomic_load(p, __ATOMIC_RELAXED, AGENT);
}
__device__ __forceinline__ void stcu(unsigned* p, unsigned v) {
    __hip_atomic_store(p, v, __ATOMIC_RELAXED, AGENT);
}

// LDS-only barrier: waits DS ops, does NOT drain vmcnt (in-flight global
// loads survive). asm memory clobbers pin IR ordering around the barrier.
__device__ __forceinline__ void ldsbar() {
    __asm__ __volatile__("s_waitcnt lgkmcnt(0)" ::: "memory");
    __builtin_amdgcn_s_barrier();
    __asm__ __volatile__("" ::: "memory");
}

// Store-flag pod barrier, all-waves-poll variant. Entry __syncthreads drains
// each wave's stores so the flag store publishes them. EVERY wave then polls
// all 64 flags (one coalesced 256B agent load per iteration) and proceeds
// independently -- no exit barrier, so staging loads issue per-wave as soon
// as readiness is visible. Safe: all LDS consumers of the previous phase
// complete before the entry sync, and writers only write after their own
// poll confirms pod-wide arrival.
__device__ __forceinline__ void podsig(unsigned* flags, int w, unsigned seq) {
    __syncthreads();
    if (threadIdx.x == 0) {
        __builtin_amdgcn_s_waitcnt(0);
        stcu(flags + w, seq);
    }
    {
        const int l = threadIdx.x & 63;
        while (ldcu(flags + l) < seq) {
            __builtin_amdgcn_s_sleep(1);
        }
    }
    __asm__ __volatile__("" ::: "memory");
}

__global__ void init_bar(int* bar) { bar[threadIdx.x] = 0; }

__device__ __forceinline__ float sigf(float x) { return 1.f / (1.f + __expf(-x)); }

// fp32 -> bf16 (RNE) and back
__device__ __forceinline__ unsigned short f2bf(float f) {
    unsigned u = __float_as_uint(f);
    return (unsigned short)((u + 0x7fffu + ((u >> 16) & 1u)) >> 16);
}
__device__ __forceinline__ float bf2f(unsigned short h) {
    return __uint_as_float(((unsigned)h) << 16);
}

// ---------------------------------------------------------------------------
// Generic fp32 GEMM: C = act(A[M,K] @ W[N,K]^T + bias). 64x64 tile.
// ---------------------------------------------------------------------------
__global__ __launch_bounds__(256) void gemm_nt(
    const float* __restrict__ A, const float* __restrict__ W,
    const float* __restrict__ bias, float* __restrict__ C,
    int M, int N, int K, int relu)
{
    __shared__ float As[16][68];
    __shared__ float Ws[16][68];
    const int tid = threadIdx.x;
    const int m0 = blockIdx.x * 64;
    const int n0 = blockIdx.y * 64;
    const int lr = tid >> 2;
    const int lk = (tid & 3) << 2;
    const int tm = (tid & 15) << 2;
    const int tn = (tid >> 4) << 2;
    float acc[4][4] = {};
    const float* Aptr = A + (size_t)(m0 + lr) * K + lk;
    const float* Wptr = W + (size_t)(n0 + lr) * K + lk;
    for (int k0 = 0; k0 < K; k0 += 16) {
        __syncthreads();
        const float4 av = *(const float4*)(Aptr + k0);
        const float4 wv = *(const float4*)(Wptr + k0);
        As[lk + 0][lr] = av.x; As[lk + 1][lr] = av.y;
        As[lk + 2][lr] = av.z; As[lk + 3][lr] = av.w;
        Ws[lk + 0][lr] = wv.x; Ws[lk + 1][lr] = wv.y;
        Ws[lk + 2][lr] = wv.z; Ws[lk + 3][lr] = wv.w;
        __syncthreads();
        #pragma unroll
        for (int kk = 0; kk < 16; ++kk) {
            float a[4], b[4];
            #pragma unroll
            for (int u = 0; u < 4; ++u) { a[u] = As[kk][tm + u]; b[u] = Ws[kk][tn + u]; }
            #pragma unroll
            for (int ii = 0; ii < 4; ++ii)
                #pragma unroll
                for (int jj = 0; jj < 4; ++jj)
                    acc[ii][jj] += a[ii] * b[jj];
        }
    }
    #pragma unroll
    for (int ii = 0; ii < 4; ++ii)
        #pragma unroll
        for (int jj = 0; jj < 4; ++jj) {
            float v = acc[ii][jj] + bias[n0 + tn + jj];
            if (relu) v = fmaxf(v, 0.f);
            C[(size_t)(m0 + tm + ii) * N + n0 + tn + jj] = v;
        }
}

// ---------------------------------------------------------------------------
// mlp0 with fused 5-way concat
// ---------------------------------------------------------------------------
__global__ __launch_bounds__(256) void gemm_cat(
    const float* __restrict__ H0, const float* __restrict__ H1,
    const float* __restrict__ H2, const float* __restrict__ feat,
    const float* __restrict__ lstm, const float* __restrict__ W,
    const float* __restrict__ bias, float* __restrict__ C)
{
    __shared__ float As[16][68];
    __shared__ float Ws[16][68];
    const int tid = threadIdx.x;
    const int m0 = blockIdx.x * 64;
    const int n0 = blockIdx.y * 64;
    const int lr = tid >> 2;
    const int lk = (tid & 3) << 2;
    const int tm = (tid & 15) << 2;
    const int tn = (tid >> 4) << 2;
    float acc[4][4] = {};
    for (int k0 = 0; k0 < 3072; k0 += 16) {
        const float* src; int kloc, Kp;
        if (k0 < 512)       { src = H0;   kloc = k0;        Kp = 512;  }
        else if (k0 < 1024) { src = H1;   kloc = k0 - 512;  Kp = 512;  }
        else if (k0 < 1536) { src = H2;   kloc = k0 - 1024; Kp = 512;  }
        else if (k0 < 2560) { src = feat; kloc = k0 - 1536; Kp = 1024; }
        else                { src = lstm; kloc = k0 - 2560; Kp = 512;  }
        __syncthreads();
        const float4 av = *(const float4*)(src + (size_t)(m0 + lr) * Kp + kloc + lk);
        const float4 wv = *(const float4*)(W + (size_t)(n0 + lr) * 3072 + k0 + lk);
        As[lk + 0][lr] = av.x; As[lk + 1][lr] = av.y;
        As[lk + 2][lr] = av.z; As[lk + 3][lr] = av.w;
        Ws[lk + 0][lr] = wv.x; Ws[lk + 1][lr] = wv.y;
        Ws[lk + 2][lr] = wv.z; Ws[lk + 3][lr] = wv.w;
        __syncthreads();
        #pragma unroll
        for (int kk = 0; kk < 16; ++kk) {
            float a[4], b[4];
            #pragma unroll
            for (int u = 0; u < 4; ++u) { a[u] = As[kk][tm + u]; b[u] = Ws[kk][tn + u]; }
            #pragma unroll
            for (int ii = 0; ii < 4; ++ii)
                #pragma unroll
                for (int jj = 0; jj < 4; ++jj)
                    acc[ii][jj] += a[ii] * b[jj];
        }
    }
    #pragma unroll
    for (int ii = 0; ii < 4; ++ii)
        #pragma unroll
        for (int jj = 0; jj < 4; ++jj) {
            float v = fmaxf(acc[ii][jj] + bias[n0 + tn + jj], 0.f);
            C[(size_t)(m0 + tm + ii) * 512 + n0 + tn + jj] = v;
        }
}

// ---------------------------------------------------------------------------
// One GNN layer scan (weight-stationary MFMA). Grid 256 (layer 0) / 128.
// LDS map (GNN):            bytes       LDS map (LSTM overlay):
//   MbU   16x520 bf16      0..16640       Msf 16x520 f32  0..33280
//   wkL   512 f32      16640..18688       lgg 512 f32 33280..35328
//   eh    16x132 f32   18688..27136
//   wsf   16x132 f32   27136..35584
//   gg    16x50  f32   35584..38784
//   invZ  16 f32       38784..38848
//   smkr  16x132 f32   38848..47296
//   VhL   16x2056 bf16 47296..112880   (slab = 128*16 + 8 pad elems)
// ---------------------------------------------------------------------------
__global__ __launch_bounds__(256, 1) void scan_layer(
    const float* __restrict__ Hin, float* __restrict__ Hout,
    const float* __restrict__ adj, const float* __restrict__ smk,
    const float* __restrict__ preQc, const float* __restrict__ preQp,
    const float* __restrict__ cWhh, const float* __restrict__ pWih,
    const float* __restrict__ cbhh, const float* __restrict__ pbih,
    const float* __restrict__ attnW,
    const float* __restrict__ Wr0, const float* __restrict__ Wr1,
    unsigned* __restrict__ Mbuf, unsigned* __restrict__ hxch,
    float* __restrict__ Vh, int* __restrict__ bar, const int with_lstm,
    const float* __restrict__ gi, const float* __restrict__ lstm_Whh,
    const float* __restrict__ lstm_bhh, float* __restrict__ lstm_hbuf,
    float* __restrict__ lstm_out, const unsigned seq0)
{
    __shared__ __align__(16) unsigned char smemc[112880];
    unsigned short* MbU = (unsigned short*)smemc;           // 16x520 bf16
    float* wkL  = (float*)(smemc + 16640);                  // 512
    float* eh   = (float*)(smemc + 18688);                  // 16x132
    float* wsf  = (float*)(smemc + 27136);                  // 16x132
    float* gg   = (float*)(smemc + 35584);                  // 16x50
    float* invZ = (float*)(smemc + 38784);                  // 16
    float* smkr = (float*)(smemc + 38848);                  // 16x132
    unsigned short* VhL = (unsigned short*)(smemc + 47296); // 16x(128*16+8)
    (void)Vh;

    const int wg = blockIdx.x, tid = threadIdx.x;

    if (wg >= 128) {
        // =========================== LSTM ================================
        if (!with_lstm) return;
        float* Msf = (float*)smemc;                      // 16x520 fp32
        float* lgg = (float*)(smemc + 33280);            // 512 fp32
        const int lw = wg - 128;
        const int lp = lw >> 6;
        const int wc = lw & 63;
        unsigned* lf = (unsigned*)bar + (2 + lp) * 64;
        const int row0 = lp * 64;
        const int u = tid & 15, rr = tid >> 4;
        const int jc = u & 7, gp = u >> 3;
        const int ghid = wc * 8 + jc;
        const float* wA = lstm_Whh + (size_t)((2 * gp) * 512 + ghid) * 512;
        const float* wB = lstm_Whh + (size_t)((2 * gp + 1) * 512 + ghid) * 512;
        const float bA = lstm_bhh[(2 * gp) * 512 + ghid];
        const float bB = lstm_bhh[(2 * gp + 1) * 512 + ghid];
        float c4[4] = {0.f, 0.f, 0.f, 0.f};
        for (int t = 0; t < 32; ++t) {
            const int par = t & 1;
            for (int rc = 0; rc < 4; ++rc) {
                const int grow = row0 + rc * 16 + rr;
                const float* gir = gi + ((size_t)t * 128 + grow) * 2048;
                // issue gi loads early (independent of staging)
                float sA = bA + gir[(2 * gp) * 512 + ghid];
                float sB = bB + gir[(2 * gp + 1) * 512 + ghid];
                if (t > 0) {
                    const float* hsrc = lstm_hbuf + (size_t)par * 65536
                                      + (size_t)(row0 + rc * 16) * 512;
                    // register-batched staging: 2 chunks of 16 pipelined loads
                    #pragma unroll
                    for (int c = 0; c < 2; ++c) {
                        float r16[16];
                        #pragma unroll
                        for (int k = 0; k < 16; ++k) {
                            const int s = tid + (c * 16 + k) * 256;
                            r16[k] = ldc(hsrc + (size_t)(s >> 9) * 512 + (s & 511));
                        }
                        #pragma unroll
                        for (int k = 0; k < 16; ++k) {
                            const int s = tid + (c * 16 + k) * 256;
                            Msf[(s >> 9) * 520 + (s & 511)] = r16[k];
                        }
                    }
                }
                __syncthreads();
                if (t > 0) {
                    const float* hr = Msf + rr * 520;
                    for (int k = 0; k < 512; k += 4) {
                        const float4 h4 = *(const float4*)(hr + k);
                        const float4 a4 = *(const float4*)(wA + k);
                        const float4 b4 = *(const float4*)(wB + k);
                        sA += h4.x*a4.x + h4.y*a4.y + h4.z*a4.z + h4.w*a4.w;
                        sB += h4.x*b4.x + h4.y*b4.y + h4.z*b4.z + h4.w*b4.w;
                    }
                }
                lgg[rr * 32 + jc * 4 + 2 * gp]     = sA;
                lgg[rr * 32 + jc * 4 + 2 * gp + 1] = sB;
                __syncthreads();
                if (tid < 128) {
                    const int r2 = tid >> 3, j2 = tid & 7;
                    const int grw = row0 + rc * 16 + r2;
                    const int gh2 = wc * 8 + j2;
                    const float si = lgg[r2 * 32 + j2 * 4 + 0];
                    const float sf = lgg[r2 * 32 + j2 * 4 + 1];
                    const float sg = lgg[r2 * 32 + j2 * 4 + 2];
                    const float so = lgg[r2 * 32 + j2 * 4 + 3];
                    const float c = sigf(sf) * c4[rc] + sigf(si) * tanhf(sg);
                    c4[rc] = c;
                    const float h = sigf(so) * tanhf(c);
                    stc(lstm_hbuf + (size_t)(1 - par) * 65536 + (size_t)grw * 512 + gh2, h);
                    lstm_out[((size_t)t * 128 + grw) * 512 + gh2] = h;
                }
                __syncthreads();
            }
            podsig(lf, wc, (unsigned)(t + 1));
            __syncthreads();
        }
        return;
    }

    // ============================= GNN ==================================
    const int pod = wg >> 6, w = wg & 63;
    unsigned* pf = (unsigned*)bar + pod * 64;
    const int b0 = pod * 16, j0 = w * 8;
    const int wv = tid >> 6, lane = tid & 63;
    const int nI = lane & 15, quad = lane >> 4;
    unsigned* MbP = Mbuf + pod * 4096;   // [16][256] bf16-pair dwords
    unsigned* hxP = hxch + pod * 4096;

    for (int s = tid; s < 512; s += 256) wkL[s] = attnW[512 + s];

    // ---- B fragments (hi/lo bf16 split), loaded ONCE into VGPRs ----
    const float* wrow;
    if (wv < 3) {
        const int c = (2 * wv + (nI >> 3)) * 512 + j0 + (nI & 7);
        wrow = (c < 1536) ? cWhh + (size_t)c * 512 : pWih + (size_t)(c - 1536) * 512;
    } else {
        wrow = ((nI >> 3) ? Wr1 : Wr0) + (size_t)(j0 + (nI & 7)) * 512;
    }
    s16x8 Bhi[16], Blo[16];
    #pragma unroll
    for (int kk = 0; kk < 16; ++kk) {
        const float* wp = wrow + kk * 32 + quad * 8;
        s16x8 hi, lo;
        #pragma unroll
        for (int e = 0; e < 8; ++e) {
            const float x = wp[e];
            const unsigned short hb = f2bf(x);
            hi[e] = (short)hb;
            lo[e] = (short)f2bf(x - bf2f(hb));
        }
        Bhi[kk] = hi; Blo[kk] = lo;
    }
    // combine-thread constants (6 gate biases for (b=tid>>3, jc=tid&7))
    const int cb_b = tid >> 3, cb_j = tid & 7;
    float gbias[6];
    if (tid < 128) {
        #pragma unroll
        for (int g = 0; g < 6; ++g) {
            const int c = g * 512 + j0 + cb_j;
            gbias[g] = (c < 1536) ? cbhh[c] : pbih[c - 1536];
        }
    }

    // persistent prefetch registers (combine inputs / attn rows)
    float cf0 = 0.f, cf1 = 0.f, cf2 = 0.f, cf3 = 0.f, cf4 = 0.f, cf5 = 0.f,
          cf6 = 0.f;
    float areg[8], sreg[8];

    // issue combine prefetch for step 0 (completes during init barrier)
    if (tid < 128) {
        const int bg = b0 + cb_b, j = j0 + cb_j;
        const float* pc = preQc + (size_t)bg * 128 * 1536;
        const float* pp = preQp + (size_t)bg * 128 * 1536;
        cf0 = pc[j]; cf1 = pc[512 + j]; cf2 = pc[1024 + j];
        cf3 = pp[j]; cf4 = pp[512 + j]; cf5 = pp[1024 + j];
        cf6 = Hin[(size_t)bg * 128 * 512 + j];
    }
    // zero M(0)
    if (w * 256 + tid < 4096) stcu(MbP + w * 256 + tid, 0u);
    podsig(pf, w, seq0 + 1);

    for (int i = 0; i < 128; ++i) {
        // ---------------- Phase 1: stage M, gate MFMA, combine h ---------
        // Issue NEXT-PHASE (phase-2) attn prefetches now: row i+1 of adj/smk.
        if (i < 127) {
            const int bq = tid >> 4, u = tid & 15;
            const float* arow = adj + ((size_t)(b0 + bq) * 128 + (i + 1)) * 128;
            #pragma unroll
            for (int kk = 0; kk < 8; ++kk) areg[kk] = arow[u + kk * 16];
            const float* sr = smk + ((size_t)b0 * 128 + (i + 1)) * 128;
            #pragma unroll
            for (int k = 0; k < 8; ++k) {
                const int s = tid + k * 256;
                sreg[k] = sr[(size_t)(s >> 7) * 16384 + (s & 127)];
            }
        }
        // register-batched M staging: issue all 16 loads, then LDS-write
        {
            unsigned mreg[16];
            #pragma unroll
            for (int k = 0; k < 16; ++k) mreg[k] = ldcu(MbP + tid + k * 256);
            #pragma unroll
            for (int k = 0; k < 16; ++k) {
                const int s = tid + k * 256;
                *(unsigned*)(MbU + (s >> 8) * 520 + ((s & 255) << 1)) = mreg[k];
            }
        }
        ldsbar();
        if (wv < 3) {
            f32x4 acc = {0.f, 0.f, 0.f, 0.f};
            const unsigned short* ab = MbU + nI * 520 + quad * 8;
            #pragma unroll
            for (int kk = 0; kk < 16; ++kk) {
                const s16x8 a = *(const s16x8*)(ab + kk * 32);
                acc = __builtin_amdgcn_mfma_f32_16x16x32_bf16(a, Bhi[kk], acc, 0, 0, 0);
                acc = __builtin_amdgcn_mfma_f32_16x16x32_bf16(a, Blo[kk], acc, 0, 0, 0);
            }
            #pragma unroll
            for (int r = 0; r < 4; ++r)
                gg[(quad * 4 + r) * 50 + wv * 16 + nI] = acc[r];
        }
        ldsbar();
        if (tid < 128) {
            const int b = cb_b, jc = cb_j, j = j0 + jc, bg = b0 + b;
            const float g0v = gg[b * 50 +  0 + jc] + gbias[0];
            const float g1v = gg[b * 50 +  8 + jc] + gbias[1];
            const float g2v = gg[b * 50 + 16 + jc] + gbias[2];
            const float g3v = gg[b * 50 + 24 + jc] + gbias[3];
            const float g4v = gg[b * 50 + 32 + jc] + gbias[4];
            const float g5v = gg[b * 50 + 40 + jc] + gbias[5];
            const float mv = bf2f(MbU[b * 520 + j]);
            const float rc = sigf(cf0 + g0v);
            const float zc = sigf(cf1 + g1v);
            const float nc = tanhf(cf2 + rc * g2v);
            const float oc = (1.f - zc) * nc + zc * mv;
            const float rp = sigf(g3v + cf3);
            const float zp = sigf(g4v + cf4);
            const float np = tanhf(g5v + rp * cf5);
            const float op = (1.f - zp) * np + zp * cf6;
            const float h = oc + op;
            Hout[((size_t)bg * 128 + i) * 512 + j] = h;
            if (i < 127) {
                // fused bf16-pair pack via lane shuffle (partner jc^1)
                const float hN = __shfl_xor(h, 1);
                if ((jc & 1) == 0) {
                    const unsigned d = (unsigned)f2bf(h)
                                     | ((unsigned)f2bf(hN) << 16);
                    stcu(hxP + b * 256 + (j0 >> 1) + (jc >> 1), d);
                }
            }
        }
        if (i == 127) break;   // h(127) written to Hout; nothing downstream
        podsig(pf, w, seq0 + 2 * i + 2);

        // ---------------- Phase 2: stage h + smk row, V MFMA, hk, softmax,
        // ---------------- M' (V history in LDS) --------------------------
        // Issue NEXT-STEP combine prefetch now (consumed in phase 1 of i+1).
        if (tid < 128) {
            const int bg = b0 + cb_b, j = j0 + cb_j;
            const float* pc = preQc + ((size_t)bg * 128 + (i + 1)) * 1536;
            const float* pp = preQp + ((size_t)bg * 128 + (i + 1)) * 1536;
            cf0 = pc[j]; cf1 = pc[512 + j]; cf2 = pc[1024 + j];
            cf3 = pp[j]; cf4 = pp[512 + j]; cf5 = pp[1024 + j];
            cf6 = Hin[((size_t)bg * 128 + (i + 1)) * 512 + j];
        }
        // register-batched h staging + smkr write from prefetched sreg
        {
            unsigned hreg[16];
            #pragma unroll
            for (int k = 0; k < 16; ++k) hreg[k] = ldcu(hxP + tid + k * 256);
            #pragma unroll
            for (int k = 0; k < 16; ++k) {
                const int s = tid + k * 256;
                *(unsigned*)(MbU + (s >> 8) * 520 + ((s & 255) << 1)) = hreg[k];
            }
            #pragma unroll
            for (int k = 0; k < 8; ++k) {
                const int s = tid + k * 256;
                smkr[(s >> 7) * 132 + (s & 127)] = sreg[k];
            }
        }
        ldsbar();
        if (wv == 3) {
            f32x4 acc = {0.f, 0.f, 0.f, 0.f};
            const unsigned short* ab = MbU + nI * 520 + quad * 8;
            #pragma unroll
            for (int kk = 0; kk < 16; ++kk) {
                const s16x8 a = *(const s16x8*)(ab + kk * 32);
                acc = __builtin_amdgcn_mfma_f32_16x16x32_bf16(a, Bhi[kk], acc, 0, 0, 0);
                acc = __builtin_amdgcn_mfma_f32_16x16x32_bf16(a, Blo[kk], acc, 0, 0, 0);
            }
            #pragma unroll
            for (int r = 0; r < 4; ++r) {
                const int b = quad * 4 + r;
                VhL[b * 2056 + i * 16 + nI] = f2bf(acc[r]);
            }
        }
        {   // hk partials (lane-contiguous) + width-16 shuffle reduce
            const int bq = tid >> 4, u = tid & 15;
            const unsigned short* hr = MbU + bq * 520;
            float p = 0.f;
            #pragma unroll
            for (int kk = 0; kk < 32; ++kk) {
                const int k = u + kk * 16;
                p += bf2f(hr[k]) * wkL[k];
            }
            #pragma unroll
            for (int off = 8; off > 0; off >>= 1) p += __shfl_xor(p, off, 16);
            if (u == 0) eh[bq * 132 + i] = p;
        }
        ldsbar();
        {
            const int bq = tid >> 4, u = tid & 15;
            float amx = -3.0e38f;
            #pragma unroll
            for (int kk = 0; kk < 8; ++kk) {
                const int n = u + kk * 16;
                if (n <= i)
                    amx = fmaxf(amx, eh[bq * 132 + n] - (1.f - areg[kk]) * 1e30f);
            }
            #pragma unroll
            for (int off = 8; off > 0; off >>= 1)
                amx = fmaxf(amx, __shfl_xor(amx, off, 16));
            float es = 0.f;
            #pragma unroll
            for (int kk = 0; kk < 8; ++kk) {
                const int n = u + kk * 16;
                if (n <= i) {
                    const float e = __expf(eh[bq * 132 + n] - (1.f - areg[kk]) * 1e30f - amx);
                    wsf[bq * 132 + n] = e;
                    es += e;
                }
            }
            #pragma unroll
            for (int off = 8; off > 0; off >>= 1) es += __shfl_xor(es, off, 16);
            if (u == 0) invZ[bq] = 1.f / es;
        }
        ldsbar();
        {
            // M' weighted sum: all 256 threads; n split even/odd by nh=u>>3.
            // Both V candidates loaded at static addresses + cndmask select
            // (no data-dependent LDS address chain).
            const int b = tid >> 4, u = tid & 15;
            const int jc2 = u & 7, nh = u >> 3;
            const float* wrow_ = wsf + b * 132;
            const float* srow_ = smkr + b * 132;
            const unsigned short* vb = VhL + b * 2056 + jc2;
            float acc2 = 0.f;
            for (int n = nh; n <= i; n += 2) {
                const float wgt = wrow_[n];
                const float sv  = srow_[n];
                const float v0 = bf2f(vb[n * 16]);
                const float v1 = bf2f(vb[n * 16 + 8]);
                acc2 += wgt * ((sv != 0.f) ? v0 : v1);
            }
            acc2 += __shfl_xor(acc2, 8, 16);
            const float mval = acc2 * invZ[b];
            // fused bf16-pair pack via lane shuffle (partner u^1)
            const float mN = __shfl_xor(mval, 1);
            if (u < 8 && (u & 1) == 0) {
                const unsigned d = (unsigned)f2bf(mval)
                                 | ((unsigned)f2bf(mN) << 16);
                stcu(MbP + b * 256 + (j0 >> 1) + (u >> 1), d);
            }
        }
        podsig(pf, w, seq0 + 2 * i + 3);
    }
}

// ---------------------------------------------------------------------------
__global__ __launch_bounds__(256) void out_gemm(
    const float* __restrict__ x2, const float* __restrict__ W,
    const float* __restrict__ bias, float* __restrict__ out)
{
    __shared__ float xs[16 * 516];
    const int tid = threadIdx.x;
    const int r0 = blockIdx.x * 16;
    for (int idx = tid; idx < 16 * 512; idx += 256) {
        const int rr = idx >> 9, kk = idx & 511;
        xs[rr * 516 + kk] = x2[(size_t)(r0 + rr) * 512 + kk];
    }
    __syncthreads();
    if (tid < 128) {
        const int r = tid >> 3, c = tid & 7;
        if (c < 7) {
            float acc = bias[c];
            const float* wr = W + c * 512;
            const float* xr = xs + r * 516;
            for (int k = 0; k < 512; ++k) acc += xr[k] * wr[k];
            out[(size_t)(r0 + r) * 7 + c] = acc;
        }
    }
}

// ---------------------------------------------------------------------------
extern "C" void kernel_launch(void* const* d_in, const int* in_sizes, int n_in,
                              void* d_out, int out_size, void* d_ws, size_t ws_size,
                              hipStream_t stream) {
    (void)in_sizes; (void)n_in; (void)out_size; (void)ws_size;
    const float* feat     = (const float*)d_in[0];
    const float* adj      = (const float*)d_in[1];
    const float* smask    = (const float*)d_in[2];
    const float* lstm_Wih = (const float*)d_in[5];
    const float* lstm_Whh = (const float*)d_in[6];
    const float* lstm_bih = (const float*)d_in[7];
    const float* lstm_bhh = (const float*)d_in[8];
    const float* fc1_W    = (const float*)d_in[9];
    const float* fc1_b    = (const float*)d_in[10];
    const float* attn_W   = (const float*)d_in[11];
    const float* Wr0      = (const float*)d_in[13];
    const float* Wr1      = (const float*)d_in[14];
    const float* gruC_Wih = (const float*)d_in[15];
    const float* gruC_Whh = (const float*)d_in[16];
    const float* gruC_bih = (const float*)d_in[17];
    const float* gruC_bhh = (const float*)d_in[18];
    const float* gruP_Wih = (const float*)d_in[19];
    const float* gruP_Whh = (const float*)d_in[20];
    const float* gruP_bih = (const float*)d_in[21];
    const float* gruP_bhh = (const float*)d_in[22];
    const float* mlp0_W   = (const float*)d_in[23];
    const float* mlp0_b   = (const float*)d_in[24];
    const float* mlp1_W   = (const float*)d_in[25];
    const float* mlp1_b   = (const float*)d_in[26];
    const float* out_W    = (const float*)d_in[27];
    const float* out_b    = (const float*)d_in[28];

    float* ws       = (float*)d_ws;
    float* lstm_gi  = ws;                        // 8,388,608
    float* lstm_out = lstm_gi + 8388608;         // 2,097,152
    float* H0       = lstm_out + 2097152;        // 2,097,152
    float* H1       = H0 + 2097152;              // 2,097,152
    float* H2       = H1 + 2097152;              // 2,097,152
    float* preQc    = H2 + 2097152;              // 6,291,456
    float* preQp    = preQc + 6291456;           // 6,291,456
    float* x1       = preQp + 6291456;           // 2,097,152
    float* x2       = x1 + 2097152;              // 2,097,152
    unsigned* Mbuf  = (unsigned*)(x2 + 2097152); // 8,192 dwords
    unsigned* hxch  = Mbuf + 8192;               // 8,192 dwords
    float* Vh       = (float*)(hxch + 8192);     // 4,194,304 (unused)
    float* lstm_hb  = Vh + 4194304;              // 131,072
    int*   bar      = (int*)(lstm_hb + 131072);  // 1,024 ints

    const dim3 blk(256);
    init_bar<<<1, 1024, 0, stream>>>(bar);

    // parallel-phase GEMMs
    gemm_nt<<<dim3(64, 8), blk, 0, stream>>>(feat, fc1_W, fc1_b, H0, 4096, 512, 1024, 1);
    gemm_nt<<<dim3(64, 32), blk, 0, stream>>>(feat, lstm_Wih, lstm_bih, lstm_gi, 4096, 2048, 1024, 0);
    gemm_nt<<<dim3(64, 24), blk, 0, stream>>>(H0, gruC_Wih, gruC_bih, preQc, 4096, 1536, 512, 0);
    gemm_nt<<<dim3(64, 24), blk, 0, stream>>>(H0, gruP_Whh, gruP_bhh, preQp, 4096, 1536, 512, 0);

    // layer 0 scan (+ LSTM on WGs 128..255); GNN flags end at seq 255
    scan_layer<<<256, blk, 0, stream>>>(
        H0, H1, adj, smask, preQc, preQp,
        gruC_Whh, gruP_Wih, gruC_bhh, gruP_bih, attn_W,
        Wr0, Wr1, Mbuf, hxch, Vh, bar, 1,
        lstm_gi, lstm_Whh, lstm_bhh, lstm_hb, lstm_out, 0u);

    // layer-1 preQ
    gemm_nt<<<dim3(64, 24), blk, 0, stream>>>(H1, gruC_Wih + (size_t)1536 * 512,
                                              gruC_bih + 1536, preQc, 4096, 1536, 512, 0);
    gemm_nt<<<dim3(64, 24), blk, 0, stream>>>(H1, gruP_Whh + (size_t)1536 * 512,
                                              gruP_bhh + 1536, preQp, 4096, 1536, 512, 0);

    // layer 1 scan (GNN only, 128 WGs); seq continues from layer 0's 255
    scan_layer<<<128, blk, 0, stream>>>(
        H1, H2, adj, smask, preQc, preQp,
        gruC_Whh + (size_t)1536 * 512, gruP_Wih + (size_t)1536 * 512,
        gruC_bhh + 1536, gruP_bih + 1536, attn_W + 1024,
        Wr0 + (size_t)512 * 512, Wr1 + (size_t)512 * 512,
        Mbuf, hxch, Vh, bar, 0,
        lstm_gi, lstm_Whh, lstm_bhh, lstm_hb, lstm_out, 255u);

    // head
    gemm_cat<<<dim3(64, 8), blk, 0, stream>>>(H0, H1, H2, feat, lstm_out, mlp0_W, mlp0_b, x1);
    gemm_nt<<<dim3(64, 8), blk, 0, stream>>>(x1, mlp1_W, mlp1_b, x2, 4096, 512, 512, 1);
    out_gemm<<<256, blk, 0, stream>>>(x2, out_W, out_b, (float*)d_out);
}

// Round 13
// 6471.320 us; speedup vs baseline: 1.3245x; 1.0044x over previous
//
#include <hip/hip_runtime.h>
#include <math.h>

// Sizes: B=32, N=128, EMB=1024, HID=512, L=2, NCLS=7, IN_DIM=3072, TOK=4096
// Scan: weight-stationary MFMA. 2 GNN pods x 64 WGs x 16 batches. Each WG
// owns 8 h-cols; waves 0-2 hold gate-weight tiles and wave 3 the V tile as
// bf16 hi/lo B-fragments in VGPRs. V history in LDS. THIS ROUND (single
// variable): podsig poll backoff changed from s_sleep(1) to a dependent-FMA
// burn of the same duration (~64cy). Hypothesis: waves parked in s_sleep at
// 6-9% occupancy let power management downclock SCLK 3-4x, uniformly
// inflating every latency (explains the 15us/phase vs ~5us modeled gap and
// why all scheduling fixes were neutral). Busy-wait keeps the CUs active.
// Cross-WG sync: store-flag barrier. LSTM on WGs 128..255 (layer-0 launch).

typedef __attribute__((ext_vector_type(4))) float f32x4;
typedef __attribute__((ext_vector_type(8))) short s16x8;

#define AGENT __HIP_MEMORY_SCOPE_AGENT

__device__ __forceinline__ float ldc(const float* p) {
    return __hip_atomic_load(p, __ATOMIC_RELAXED, AGENT);
}
__device__ __forceinline__ void stc(float* p, float v) {
    __hip_atomic_store(p, v, __ATOMIC_RELAXED, AGENT);
}
__device__ __forceinline__ unsigned ldcu(const unsigned* p) {
    return __hip_atomic_load(p, __ATOMIC_RELAXED, AGENT);
}
__device__ __forceinline__ void stcu(unsigned* p, unsigned v) {
    __hip_atomic_store(p, v, __ATOMIC_RELAXED, AGENT);
}

// LDS-only barrier: waits DS ops, does NOT drain vmcnt (in-flight global
// loads survive). asm memory clobbers pin IR ordering around the barrier.
__device__ __forceinline__ void ldsbar() {
    __asm__ __volatile__("s_waitcnt lgkmcnt(0)" ::: "memory");
    __builtin_amdgcn_s_barrier();
    __asm__ __volatile__("" ::: "memory");
}

// Store-flag pod barrier, all-waves-poll variant. Entry __syncthreads drains
// each wave's stores so the flag store publishes them. EVERY wave polls all
// 64 flags (one coalesced 256B agent load per iteration). Poll backoff is a
// dependent-FMA burn (~64cy, same cadence as s_sleep(1)) that keeps the
// SIMDs busy so power management holds clocks up; result kept live via asm
// sink (DCE guard).
__device__ __forceinline__ void podsig(unsigned* flags, int w, unsigned seq) {
    __syncthreads();
    if (threadIdx.x == 0) {
        __builtin_amdgcn_s_waitcnt(0);
        stcu(flags + w, seq);
    }
    {
        const int l = threadIdx.x & 63;
        float x = (float)seq;
        while (ldcu(flags + l) < seq) {
            #pragma unroll
            for (int z = 0; z < 16; ++z)
                x = __builtin_fmaf(x, 1.0000001f, 1e-30f);
        }
        __asm__ __volatile__("" :: "v"(x));
    }
    __asm__ __volatile__("" ::: "memory");
}

__global__ void init_bar(int* bar) { bar[threadIdx.x] = 0; }

__device__ __forceinline__ float sigf(float x) { return 1.f / (1.f + __expf(-x)); }

// fp32 -> bf16 (RNE) and back
__device__ __forceinline__ unsigned short f2bf(float f) {
    unsigned u = __float_as_uint(f);
    return (unsigned short)((u + 0x7fffu + ((u >> 16) & 1u)) >> 16);
}
__device__ __forceinline__ float bf2f(unsigned short h) {
    return __uint_as_float(((unsigned)h) << 16);
}

// ---------------------------------------------------------------------------
// Generic fp32 GEMM: C = act(A[M,K] @ W[N,K]^T + bias). 64x64 tile.
// ---------------------------------------------------------------------------
__global__ __launch_bounds__(256) void gemm_nt(
    const float* __restrict__ A, const float* __restrict__ W,
    const float* __restrict__ bias, float* __restrict__ C,
    int M, int N, int K, int relu)
{
    __shared__ float As[16][68];
    __shared__ float Ws[16][68];
    const int tid = threadIdx.x;
    const int m0 = blockIdx.x * 64;
    const int n0 = blockIdx.y * 64;
    const int lr = tid >> 2;
    const int lk = (tid & 3) << 2;
    const int tm = (tid & 15) << 2;
    const int tn = (tid >> 4) << 2;
    float acc[4][4] = {};
    const float* Aptr = A + (size_t)(m0 + lr) * K + lk;
    const float* Wptr = W + (size_t)(n0 + lr) * K + lk;
    for (int k0 = 0; k0 < K; k0 += 16) {
        __syncthreads();
        const float4 av = *(const float4*)(Aptr + k0);
        const float4 wv = *(const float4*)(Wptr + k0);
        As[lk + 0][lr] = av.x; As[lk + 1][lr] = av.y;
        As[lk + 2][lr] = av.z; As[lk + 3][lr] = av.w;
        Ws[lk + 0][lr] = wv.x; Ws[lk + 1][lr] = wv.y;
        Ws[lk + 2][lr] = wv.z; Ws[lk + 3][lr] = wv.w;
        __syncthreads();
        #pragma unroll
        for (int kk = 0; kk < 16; ++kk) {
            float a[4], b[4];
            #pragma unroll
            for (int u = 0; u < 4; ++u) { a[u] = As[kk][tm + u]; b[u] = Ws[kk][tn + u]; }
            #pragma unroll
            for (int ii = 0; ii < 4; ++ii)
                #pragma unroll
                for (int jj = 0; jj < 4; ++jj)
                    acc[ii][jj] += a[ii] * b[jj];
        }
    }
    #pragma unroll
    for (int ii = 0; ii < 4; ++ii)
        #pragma unroll
        for (int jj = 0; jj < 4; ++jj) {
            float v = acc[ii][jj] + bias[n0 + tn + jj];
            if (relu) v = fmaxf(v, 0.f);
            C[(size_t)(m0 + tm + ii) * N + n0 + tn + jj] = v;
        }
}

// ---------------------------------------------------------------------------
// mlp0 with fused 5-way concat
// ---------------------------------------------------------------------------
__global__ __launch_bounds__(256) void gemm_cat(
    const float* __restrict__ H0, const float* __restrict__ H1,
    const float* __restrict__ H2, const float* __restrict__ feat,
    const float* __restrict__ lstm, const float* __restrict__ W,
    const float* __restrict__ bias, float* __restrict__ C)
{
    __shared__ float As[16][68];
    __shared__ float Ws[16][68];
    const int tid = threadIdx.x;
    const int m0 = blockIdx.x * 64;
    const int n0 = blockIdx.y * 64;
    const int lr = tid >> 2;
    const int lk = (tid & 3) << 2;
    const int tm = (tid & 15) << 2;
    const int tn = (tid >> 4) << 2;
    float acc[4][4] = {};
    for (int k0 = 0; k0 < 3072; k0 += 16) {
        const float* src; int kloc, Kp;
        if (k0 < 512)       { src = H0;   kloc = k0;        Kp = 512;  }
        else if (k0 < 1024) { src = H1;   kloc = k0 - 512;  Kp = 512;  }
        else if (k0 < 1536) { src = H2;   kloc = k0 - 1024; Kp = 512;  }
        else if (k0 < 2560) { src = feat; kloc = k0 - 1536; Kp = 1024; }
        else                { src = lstm; kloc = k0 - 2560; Kp = 512;  }
        __syncthreads();
        const float4 av = *(const float4*)(src + (size_t)(m0 + lr) * Kp + kloc + lk);
        const float4 wv = *(const float4*)(W + (size_t)(n0 + lr) * 3072 + k0 + lk);
        As[lk + 0][lr] = av.x; As[lk + 1][lr] = av.y;
        As[lk + 2][lr] = av.z; As[lk + 3][lr] = av.w;
        Ws[lk + 0][lr] = wv.x; Ws[lk + 1][lr] = wv.y;
        Ws[lk + 2][lr] = wv.z; Ws[lk + 3][lr] = wv.w;
        __syncthreads();
        #pragma unroll
        for (int kk = 0; kk < 16; ++kk) {
            float a[4], b[4];
            #pragma unroll
            for (int u = 0; u < 4; ++u) { a[u] = As[kk][tm + u]; b[u] = Ws[kk][tn + u]; }
            #pragma unroll
            for (int ii = 0; ii < 4; ++ii)
                #pragma unroll
                for (int jj = 0; jj < 4; ++jj)
                    acc[ii][jj] += a[ii] * b[jj];
        }
    }
    #pragma unroll
    for (int ii = 0; ii < 4; ++ii)
        #pragma unroll
        for (int jj = 0; jj < 4; ++jj) {
            float v = fmaxf(acc[ii][jj] + bias[n0 + tn + jj], 0.f);
            C[(size_t)(m0 + tm + ii) * 512 + n0 + tn + jj] = v;
        }
}

// ---------------------------------------------------------------------------
// One GNN layer scan (weight-stationary MFMA). Grid 256 (layer 0) / 128.
// LDS map (GNN):            bytes       LDS map (LSTM overlay):
//   MbU   16x520 bf16      0..16640       Msf 16x520 f32  0..33280
//   wkL   512 f32      16640..18688       lgg 512 f32 33280..35328
//   eh    16x132 f32   18688..27136
//   wsf   16x132 f32   27136..35584
//   gg    16x50  f32   35584..38784
//   invZ  16 f32       38784..38848
//   smkr  16x132 f32   38848..47296
//   VhL   16x2056 bf16 47296..112880   (slab = 128*16 + 8 pad elems)
// ---------------------------------------------------------------------------
__global__ __launch_bounds__(256, 1) void scan_layer(
    const float* __restrict__ Hin, float* __restrict__ Hout,
    const float* __restrict__ adj, const float* __restrict__ smk,
    const float* __restrict__ preQc, const float* __restrict__ preQp,
    const float* __restrict__ cWhh, const float* __restrict__ pWih,
    const float* __restrict__ cbhh, const float* __restrict__ pbih,
    const float* __restrict__ attnW,
    const float* __restrict__ Wr0, const float* __restrict__ Wr1,
    unsigned* __restrict__ Mbuf, unsigned* __restrict__ hxch,
    float* __restrict__ Vh, int* __restrict__ bar, const int with_lstm,
    const float* __restrict__ gi, const float* __restrict__ lstm_Whh,
    const float* __restrict__ lstm_bhh, float* __restrict__ lstm_hbuf,
    float* __restrict__ lstm_out, const unsigned seq0)
{
    __shared__ __align__(16) unsigned char smemc[112880];
    unsigned short* MbU = (unsigned short*)smemc;           // 16x520 bf16
    float* wkL  = (float*)(smemc + 16640);                  // 512
    float* eh   = (float*)(smemc + 18688);                  // 16x132
    float* wsf  = (float*)(smemc + 27136);                  // 16x132
    float* gg   = (float*)(smemc + 35584);                  // 16x50
    float* invZ = (float*)(smemc + 38784);                  // 16
    float* smkr = (float*)(smemc + 38848);                  // 16x132
    unsigned short* VhL = (unsigned short*)(smemc + 47296); // 16x(128*16+8)
    (void)Vh;

    const int wg = blockIdx.x, tid = threadIdx.x;

    if (wg >= 128) {
        // =========================== LSTM ================================
        if (!with_lstm) return;
        float* Msf = (float*)smemc;                      // 16x520 fp32
        float* lgg = (float*)(smemc + 33280);            // 512 fp32
        const int lw = wg - 128;
        const int lp = lw >> 6;
        const int wc = lw & 63;
        unsigned* lf = (unsigned*)bar + (2 + lp) * 64;
        const int row0 = lp * 64;
        const int u = tid & 15, rr = tid >> 4;
        const int jc = u & 7, gp = u >> 3;
        const int ghid = wc * 8 + jc;
        const float* wA = lstm_Whh + (size_t)((2 * gp) * 512 + ghid) * 512;
        const float* wB = lstm_Whh + (size_t)((2 * gp + 1) * 512 + ghid) * 512;
        const float bA = lstm_bhh[(2 * gp) * 512 + ghid];
        const float bB = lstm_bhh[(2 * gp + 1) * 512 + ghid];
        float c4[4] = {0.f, 0.f, 0.f, 0.f};
        for (int t = 0; t < 32; ++t) {
            const int par = t & 1;
            for (int rc = 0; rc < 4; ++rc) {
                const int grow = row0 + rc * 16 + rr;
                const float* gir = gi + ((size_t)t * 128 + grow) * 2048;
                // issue gi loads early (independent of staging)
                float sA = bA + gir[(2 * gp) * 512 + ghid];
                float sB = bB + gir[(2 * gp + 1) * 512 + ghid];
                if (t > 0) {
                    const float* hsrc = lstm_hbuf + (size_t)par * 65536
                                      + (size_t)(row0 + rc * 16) * 512;
                    // register-batched staging: 2 chunks of 16 pipelined loads
                    #pragma unroll
                    for (int c = 0; c < 2; ++c) {
                        float r16[16];
                        #pragma unroll
                        for (int k = 0; k < 16; ++k) {
                            const int s = tid + (c * 16 + k) * 256;
                            r16[k] = ldc(hsrc + (size_t)(s >> 9) * 512 + (s & 511));
                        }
                        #pragma unroll
                        for (int k = 0; k < 16; ++k) {
                            const int s = tid + (c * 16 + k) * 256;
                            Msf[(s >> 9) * 520 + (s & 511)] = r16[k];
                        }
                    }
                }
                __syncthreads();
                if (t > 0) {
                    const float* hr = Msf + rr * 520;
                    for (int k = 0; k < 512; k += 4) {
                        const float4 h4 = *(const float4*)(hr + k);
                        const float4 a4 = *(const float4*)(wA + k);
                        const float4 b4 = *(const float4*)(wB + k);
                        sA += h4.x*a4.x + h4.y*a4.y + h4.z*a4.z + h4.w*a4.w;
                        sB += h4.x*b4.x + h4.y*b4.y + h4.z*b4.z + h4.w*b4.w;
                    }
                }
                lgg[rr * 32 + jc * 4 + 2 * gp]     = sA;
                lgg[rr * 32 + jc * 4 + 2 * gp + 1] = sB;
                __syncthreads();
                if (tid < 128) {
                    const int r2 = tid >> 3, j2 = tid & 7;
                    const int grw = row0 + rc * 16 + r2;
                    const int gh2 = wc * 8 + j2;
                    const float si = lgg[r2 * 32 + j2 * 4 + 0];
                    const float sf = lgg[r2 * 32 + j2 * 4 + 1];
                    const float sg = lgg[r2 * 32 + j2 * 4 + 2];
                    const float so = lgg[r2 * 32 + j2 * 4 + 3];
                    const float c = sigf(sf) * c4[rc] + sigf(si) * tanhf(sg);
                    c4[rc] = c;
                    const float h = sigf(so) * tanhf(c);
                    stc(lstm_hbuf + (size_t)(1 - par) * 65536 + (size_t)grw * 512 + gh2, h);
                    lstm_out[((size_t)t * 128 + grw) * 512 + gh2] = h;
                }
                __syncthreads();
            }
            podsig(lf, wc, (unsigned)(t + 1));
            __syncthreads();
        }
        return;
    }

    // ============================= GNN ==================================
    const int pod = wg >> 6, w = wg & 63;
    unsigned* pf = (unsigned*)bar + pod * 64;
    const int b0 = pod * 16, j0 = w * 8;
    const int wv = tid >> 6, lane = tid & 63;
    const int nI = lane & 15, quad = lane >> 4;
    unsigned* MbP = Mbuf + pod * 4096;   // [16][256] bf16-pair dwords
    unsigned* hxP = hxch + pod * 4096;

    for (int s = tid; s < 512; s += 256) wkL[s] = attnW[512 + s];

    // ---- B fragments (hi/lo bf16 split), loaded ONCE into VGPRs ----
    const float* wrow;
    if (wv < 3) {
        const int c = (2 * wv + (nI >> 3)) * 512 + j0 + (nI & 7);
        wrow = (c < 1536) ? cWhh + (size_t)c * 512 : pWih + (size_t)(c - 1536) * 512;
    } else {
        wrow = ((nI >> 3) ? Wr1 : Wr0) + (size_t)(j0 + (nI & 7)) * 512;
    }
    s16x8 Bhi[16], Blo[16];
    #pragma unroll
    for (int kk = 0; kk < 16; ++kk) {
        const float* wp = wrow + kk * 32 + quad * 8;
        s16x8 hi, lo;
        #pragma unroll
        for (int e = 0; e < 8; ++e) {
            const float x = wp[e];
            const unsigned short hb = f2bf(x);
            hi[e] = (short)hb;
            lo[e] = (short)f2bf(x - bf2f(hb));
        }
        Bhi[kk] = hi; Blo[kk] = lo;
    }
    // combine-thread constants (6 gate biases for (b=tid>>3, jc=tid&7))
    const int cb_b = tid >> 3, cb_j = tid & 7;
    float gbias[6];
    if (tid < 128) {
        #pragma unroll
        for (int g = 0; g < 6; ++g) {
            const int c = g * 512 + j0 + cb_j;
            gbias[g] = (c < 1536) ? cbhh[c] : pbih[c - 1536];
        }
    }

    // persistent prefetch registers (combine inputs / attn rows)
    float cf0 = 0.f, cf1 = 0.f, cf2 = 0.f, cf3 = 0.f, cf4 = 0.f, cf5 = 0.f,
          cf6 = 0.f;
    float areg[8], sreg[8];

    // issue combine prefetch for step 0 (completes during init barrier)
    if (tid < 128) {
        const int bg = b0 + cb_b, j = j0 + cb_j;
        const float* pc = preQc + (size_t)bg * 128 * 1536;
        const float* pp = preQp + (size_t)bg * 128 * 1536;
        cf0 = pc[j]; cf1 = pc[512 + j]; cf2 = pc[1024 + j];
        cf3 = pp[j]; cf4 = pp[512 + j]; cf5 = pp[1024 + j];
        cf6 = Hin[(size_t)bg * 128 * 512 + j];
    }
    // zero M(0)
    if (w * 256 + tid < 4096) stcu(MbP + w * 256 + tid, 0u);
    podsig(pf, w, seq0 + 1);

    for (int i = 0; i < 128; ++i) {
        // ---------------- Phase 1: stage M, gate MFMA, combine h ---------
        // Issue NEXT-PHASE (phase-2) attn prefetches now: row i+1 of adj/smk.
        if (i < 127) {
            const int bq = tid >> 4, u = tid & 15;
            const float* arow = adj + ((size_t)(b0 + bq) * 128 + (i + 1)) * 128;
            #pragma unroll
            for (int kk = 0; kk < 8; ++kk) areg[kk] = arow[u + kk * 16];
            const float* sr = smk + ((size_t)b0 * 128 + (i + 1)) * 128;
            #pragma unroll
            for (int k = 0; k < 8; ++k) {
                const int s = tid + k * 256;
                sreg[k] = sr[(size_t)(s >> 7) * 16384 + (s & 127)];
            }
        }
        // register-batched M staging: issue all 16 loads, then LDS-write
        {
            unsigned mreg[16];
            #pragma unroll
            for (int k = 0; k < 16; ++k) mreg[k] = ldcu(MbP + tid + k * 256);
            #pragma unroll
            for (int k = 0; k < 16; ++k) {
                const int s = tid + k * 256;
                *(unsigned*)(MbU + (s >> 8) * 520 + ((s & 255) << 1)) = mreg[k];
            }
        }
        ldsbar();
        if (wv < 3) {
            f32x4 acc = {0.f, 0.f, 0.f, 0.f};
            const unsigned short* ab = MbU + nI * 520 + quad * 8;
            #pragma unroll
            for (int kk = 0; kk < 16; ++kk) {
                const s16x8 a = *(const s16x8*)(ab + kk * 32);
                acc = __builtin_amdgcn_mfma_f32_16x16x32_bf16(a, Bhi[kk], acc, 0, 0, 0);
                acc = __builtin_amdgcn_mfma_f32_16x16x32_bf16(a, Blo[kk], acc, 0, 0, 0);
            }
            #pragma unroll
            for (int r = 0; r < 4; ++r)
                gg[(quad * 4 + r) * 50 + wv * 16 + nI] = acc[r];
        }
        ldsbar();
        if (tid < 128) {
            const int b = cb_b, jc = cb_j, j = j0 + jc, bg = b0 + b;
            const float g0v = gg[b * 50 +  0 + jc] + gbias[0];
            const float g1v = gg[b * 50 +  8 + jc] + gbias[1];
            const float g2v = gg[b * 50 + 16 + jc] + gbias[2];
            const float g3v = gg[b * 50 + 24 + jc] + gbias[3];
            const float g4v = gg[b * 50 + 32 + jc] + gbias[4];
            const float g5v = gg[b * 50 + 40 + jc] + gbias[5];
            const float mv = bf2f(MbU[b * 520 + j]);
            const float rc = sigf(cf0 + g0v);
            const float zc = sigf(cf1 + g1v);
            const float nc = tanhf(cf2 + rc * g2v);
            const float oc = (1.f - zc) * nc + zc * mv;
            const float rp = sigf(g3v + cf3);
            const float zp = sigf(g4v + cf4);
            const float np = tanhf(g5v + rp * cf5);
            const float op = (1.f - zp) * np + zp * cf6;
            const float h = oc + op;
            Hout[((size_t)bg * 128 + i) * 512 + j] = h;
            if (i < 127) {
                // fused bf16-pair pack via lane shuffle (partner jc^1)
                const float hN = __shfl_xor(h, 1);
                if ((jc & 1) == 0) {
                    const unsigned d = (unsigned)f2bf(h)
                                     | ((unsigned)f2bf(hN) << 16);
                    stcu(hxP + b * 256 + (j0 >> 1) + (jc >> 1), d);
                }
            }
        }
        if (i == 127) break;   // h(127) written to Hout; nothing downstream
        podsig(pf, w, seq0 + 2 * i + 2);

        // ---------------- Phase 2: stage h + smk row, V MFMA, hk, softmax,
        // ---------------- M' (V history in LDS) --------------------------
        // Issue NEXT-STEP combine prefetch now (consumed in phase 1 of i+1).
        if (tid < 128) {
            const int bg = b0 + cb_b, j = j0 + cb_j;
            const float* pc = preQc + ((size_t)bg * 128 + (i + 1)) * 1536;
            const float* pp = preQp + ((size_t)bg * 128 + (i + 1)) * 1536;
            cf0 = pc[j]; cf1 = pc[512 + j]; cf2 = pc[1024 + j];
            cf3 = pp[j]; cf4 = pp[512 + j]; cf5 = pp[1024 + j];
            cf6 = Hin[((size_t)bg * 128 + (i + 1)) * 512 + j];
        }
        // register-batched h staging + smkr write from prefetched sreg
        {
            unsigned hreg[16];
            #pragma unroll
            for (int k = 0; k < 16; ++k) hreg[k] = ldcu(hxP + tid + k * 256);
            #pragma unroll
            for (int k = 0; k < 16; ++k) {
                const int s = tid + k * 256;
                *(unsigned*)(MbU + (s >> 8) * 520 + ((s & 255) << 1)) = hreg[k];
            }
            #pragma unroll
            for (int k = 0; k < 8; ++k) {
                const int s = tid + k * 256;
                smkr[(s >> 7) * 132 + (s & 127)] = sreg[k];
            }
        }
        ldsbar();
        if (wv == 3) {
            f32x4 acc = {0.f, 0.f, 0.f, 0.f};
            const unsigned short* ab = MbU + nI * 520 + quad * 8;
            #pragma unroll
            for (int kk = 0; kk < 16; ++kk) {
                const s16x8 a = *(const s16x8*)(ab + kk * 32);
                acc = __builtin_amdgcn_mfma_f32_16x16x32_bf16(a, Bhi[kk], acc, 0, 0, 0);
                acc = __builtin_amdgcn_mfma_f32_16x16x32_bf16(a, Blo[kk], acc, 0, 0, 0);
            }
            #pragma unroll
            for (int r = 0; r < 4; ++r) {
                const int b = quad * 4 + r;
                VhL[b * 2056 + i * 16 + nI] = f2bf(acc[r]);
            }
        }
        {   // hk partials (lane-contiguous) + width-16 shuffle reduce
            const int bq = tid >> 4, u = tid & 15;
            const unsigned short* hr = MbU + bq * 520;
            float p = 0.f;
            #pragma unroll
            for (int kk = 0; kk < 32; ++kk) {
                const int k = u + kk * 16;
                p += bf2f(hr[k]) * wkL[k];
            }
            #pragma unroll
            for (int off = 8; off > 0; off >>= 1) p += __shfl_xor(p, off, 16);
            if (u == 0) eh[bq * 132 + i] = p;
        }
        ldsbar();
        {
            const int bq = tid >> 4, u = tid & 15;
            float amx = -3.0e38f;
            #pragma unroll
            for (int kk = 0; kk < 8; ++kk) {
                const int n = u + kk * 16;
                if (n <= i)
                    amx = fmaxf(amx, eh[bq * 132 + n] - (1.f - areg[kk]) * 1e30f);
            }
            #pragma unroll
            for (int off = 8; off > 0; off >>= 1)
                amx = fmaxf(amx, __shfl_xor(amx, off, 16));
            float es = 0.f;
            #pragma unroll
            for (int kk = 0; kk < 8; ++kk) {
                const int n = u + kk * 16;
                if (n <= i) {
                    const float e = __expf(eh[bq * 132 + n] - (1.f - areg[kk]) * 1e30f - amx);
                    wsf[bq * 132 + n] = e;
                    es += e;
                }
            }
            #pragma unroll
            for (int off = 8; off > 0; off >>= 1) es += __shfl_xor(es, off, 16);
            if (u == 0) invZ[bq] = 1.f / es;
        }
        ldsbar();
        {
            // M' weighted sum: all 256 threads; n split even/odd by nh=u>>3.
            // Both V candidates loaded at static addresses + cndmask select
            // (no data-dependent LDS address chain).
            const int b = tid >> 4, u = tid & 15;
            const int jc2 = u & 7, nh = u >> 3;
            const float* wrow_ = wsf + b * 132;
            const float* srow_ = smkr + b * 132;
            const unsigned short* vb = VhL + b * 2056 + jc2;
            float acc2 = 0.f;
            for (int n = nh; n <= i; n += 2) {
                const float wgt = wrow_[n];
                const float sv  = srow_[n];
                const float v0 = bf2f(vb[n * 16]);
                const float v1 = bf2f(vb[n * 16 + 8]);
                acc2 += wgt * ((sv != 0.f) ? v0 : v1);
            }
            acc2 += __shfl_xor(acc2, 8, 16);
            const float mval = acc2 * invZ[b];
            // fused bf16-pair pack via lane shuffle (partner u^1)
            const float mN = __shfl_xor(mval, 1);
            if (u < 8 && (u & 1) == 0) {
                const unsigned d = (unsigned)f2bf(mval)
                                 | ((unsigned)f2bf(mN) << 16);
                stcu(MbP + b * 256 + (j0 >> 1) + (u >> 1), d);
            }
        }
        podsig(pf, w, seq0 + 2 * i + 3);
    }
}

// ---------------------------------------------------------------------------
__global__ __launch_bounds__(256) void out_gemm(
    const float* __restrict__ x2, const float* __restrict__ W,
    const float* __restrict__ bias, float* __restrict__ out)
{
    __shared__ float xs[16 * 516];
    const int tid = threadIdx.x;
    const int r0 = blockIdx.x * 16;
    for (int idx = tid; idx < 16 * 512; idx += 256) {
        const int rr = idx >> 9, kk = idx & 511;
        xs[rr * 516 + kk] = x2[(size_t)(r0 + rr) * 512 + kk];
    }
    __syncthreads();
    if (tid < 128) {
        const int r = tid >> 3, c = tid & 7;
        if (c < 7) {
            float acc = bias[c];
            const float* wr = W + c * 512;
            const float* xr = xs + r * 516;
            for (int k = 0; k < 512; ++k) acc += xr[k] * wr[k];
            out[(size_t)(r0 + r) * 7 + c] = acc;
        }
    }
}

// ---------------------------------------------------------------------------
extern "C" void kernel_launch(void* const* d_in, const int* in_sizes, int n_in,
                              void* d_out, int out_size, void* d_ws, size_t ws_size,
                              hipStream_t stream) {
    (void)in_sizes; (void)n_in; (void)out_size; (void)ws_size;
    const float* feat     = (const float*)d_in[0];
    const float* adj      = (const float*)d_in[1];
    const float* smask    = (const float*)d_in[2];
    const float* lstm_Wih = (const float*)d_in[5];
    const float* lstm_Whh = (const float*)d_in[6];
    const float* lstm_bih = (const float*)d_in[7];
    const float* lstm_bhh = (const float*)d_in[8];
    const float* fc1_W    = (const float*)d_in[9];
    const float* fc1_b    = (const float*)d_in[10];
    const float* attn_W   = (const float*)d_in[11];
    const float* Wr0      = (const float*)d_in[13];
    const float* Wr1      = (const float*)d_in[14];
    const float* gruC_Wih = (const float*)d_in[15];
    const float* gruC_Whh = (const float*)d_in[16];
    const float* gruC_bih = (const float*)d_in[17];
    const float* gruC_bhh = (const float*)d_in[18];
    const float* gruP_Wih = (const float*)d_in[19];
    const float* gruP_Whh = (const float*)d_in[20];
    const float* gruP_bih = (const float*)d_in[21];
    const float* gruP_bhh = (const float*)d_in[22];
    const float* mlp0_W   = (const float*)d_in[23];
    const float* mlp0_b   = (const float*)d_in[24];
    const float* mlp1_W   = (const float*)d_in[25];
    const float* mlp1_b   = (const float*)d_in[26];
    const float* out_W    = (const float*)d_in[27];
    const float* out_b    = (const float*)d_in[28];

    float* ws       = (float*)d_ws;
    float* lstm_gi  = ws;                        // 8,388,608
    float* lstm_out = lstm_gi + 8388608;         // 2,097,152
    float* H0       = lstm_out + 2097152;        // 2,097,152
    float* H1       = H0 + 2097152;              // 2,097,152
    float* H2       = H1 + 2097152;              // 2,097,152
    float* preQc    = H2 + 2097152;              // 6,291,456
    float* preQp    = preQc + 6291456;           // 6,291,456
    float* x1       = preQp + 6291456;           // 2,097,152
    float* x2       = x1 + 2097152;              // 2,097,152
    unsigned* Mbuf  = (unsigned*)(x2 + 2097152); // 8,192 dwords
    unsigned* hxch  = Mbuf + 8192;               // 8,192 dwords
    float* Vh       = (float*)(hxch + 8192);     // 4,194,304 (unused)
    float* lstm_hb  = Vh + 4194304;              // 131,072
    int*   bar      = (int*)(lstm_hb + 131072);  // 1,024 ints

    const dim3 blk(256);
    init_bar<<<1, 1024, 0, stream>>>(bar);

    // parallel-phase GEMMs
    gemm_nt<<<dim3(64, 8), blk, 0, stream>>>(feat, fc1_W, fc1_b, H0, 4096, 512, 1024, 1);
    gemm_nt<<<dim3(64, 32), blk, 0, stream>>>(feat, lstm_Wih, lstm_bih, lstm_gi, 4096, 2048, 1024, 0);
    gemm_nt<<<dim3(64, 24), blk, 0, stream>>>(H0, gruC_Wih, gruC_bih, preQc, 4096, 1536, 512, 0);
    gemm_nt<<<dim3(64, 24), blk, 0, stream>>>(H0, gruP_Whh, gruP_bhh, preQp, 4096, 1536, 512, 0);

    // layer 0 scan (+ LSTM on WGs 128..255); GNN flags end at seq 255
    scan_layer<<<256, blk, 0, stream>>>(
        H0, H1, adj, smask, preQc, preQp,
        gruC_Whh, gruP_Wih, gruC_bhh, gruP_bih, attn_W,
        Wr0, Wr1, Mbuf, hxch, Vh, bar, 1,
        lstm_gi, lstm_Whh, lstm_bhh, lstm_hb, lstm_out, 0u);

    // layer-1 preQ
    gemm_nt<<<dim3(64, 24), blk, 0, stream>>>(H1, gruC_Wih + (size_t)1536 * 512,
                                              gruC_bih + 1536, preQc, 4096, 1536, 512, 0);
    gemm_nt<<<dim3(64, 24), blk, 0, stream>>>(H1, gruP_Whh + (size_t)1536 * 512,
                                              gruP_bhh + 1536, preQp, 4096, 1536, 512, 0);

    // layer 1 scan (GNN only, 128 WGs); seq continues from layer 0's 255
    scan_layer<<<128, blk, 0, stream>>>(
        H1, H2, adj, smask, preQc, preQp,
        gruC_Whh + (size_t)1536 * 512, gruP_Wih + (size_t)1536 * 512,
        gruC_bhh + 1536, gruP_bih + 1536, attn_W + 1024,
        Wr0 + (size_t)512 * 512, Wr1 + (size_t)512 * 512,
        Mbuf, hxch, Vh, bar, 0,
        lstm_gi, lstm_Whh, lstm_bhh, lstm_hb, lstm_out, 255u);

    // head
    gemm_cat<<<dim3(64, 8), blk, 0, stream>>>(H0, H1, H2, feat, lstm_out, mlp0_W, mlp0_b, x1);
    gemm_nt<<<dim3(64, 8), blk, 0, stream>>>(x1, mlp1_W, mlp1_b, x2, 4096, 512, 512, 1);
    out_gemm<<<256, blk, 0, stream>>>(x2, out_W, out_b, (float*)d_out);
}